// Round 5
// baseline (1387.670 us; speedup 1.0000x reference)
//
#include <hip/hip_runtime.h>
#include <hip/hip_bf16.h>
#include <math.h>

#define NHh   8
#define EMB   256
#define HDd   32
#define NVv   6
#define SLENs 5440
#define QQ    1600
#define A_ATTN 3072   // NH*NV*NL*NP*NZ
#define A_OFF  6144
#define SAMP_TOT (QQ * A_ATTN)   // 4,915,200

typedef __attribute__((ext_vector_type(8))) short short8;
typedef __attribute__((ext_vector_type(4))) float f32x4;

__device__ __forceinline__ unsigned short f2bf(float f) {
  __hip_bfloat16 h = __float2bfloat16(f);
  return *(unsigned short*)&h;
}
__device__ __forceinline__ float bf2f(unsigned short u) {
  return __uint_as_float((unsigned int)u << 16);
}

// ---------------------------------------------------------------------------
// One-shot fp32 -> bf16 hi(/lo) split of all GEMM operands.
// Segments in float4 units (sizes fixed by the problem).
// ---------------------------------------------------------------------------
__global__ __launch_bounds__(256) void split_all_kernel(
    const float* __restrict__ q, const float* __restrict__ value,
    const float* __restrict__ Woff, const float* __restrict__ Wattn,
    const float* __restrict__ Wv, const float* __restrict__ Wout,
    unsigned short* __restrict__ qh, unsigned short* __restrict__ ql,
    unsigned short* __restrict__ vh,
    unsigned short* __restrict__ Woffh, unsigned short* __restrict__ Woffl,
    unsigned short* __restrict__ Wattnh, unsigned short* __restrict__ Wattnl,
    unsigned short* __restrict__ Wvh,
    unsigned short* __restrict__ Wouth, unsigned short* __restrict__ Woutl) {
  int i4 = blockIdx.x * 256 + threadIdx.x;   // < 2,813,952
  const float* src; unsigned short* dh; unsigned short* dl; int loc;
  if      (i4 < 102400)  { src = q;     dh = qh;     dl = ql;     loc = i4; }
  else if (i4 < 2191360) { src = value; dh = vh;     dl = nullptr; loc = i4 - 102400; }
  else if (i4 < 2584576) { src = Woff;  dh = Woffh;  dl = Woffl;  loc = i4 - 2191360; }
  else if (i4 < 2781184) { src = Wattn; dh = Wattnh; dl = Wattnl; loc = i4 - 2584576; }
  else if (i4 < 2797568) { src = Wv;    dh = Wvh;    dl = nullptr; loc = i4 - 2781184; }
  else                   { src = Wout;  dh = Wouth;  dl = Woutl;  loc = i4 - 2797568; }
  float4 x = ((const float4*)src)[loc];
  ushort4 hh;
  hh.x = f2bf(x.x); hh.y = f2bf(x.y); hh.z = f2bf(x.z); hh.w = f2bf(x.w);
  ((ushort4*)dh)[loc] = hh;
  if (dl) {
    ushort4 ll;
    ll.x = f2bf(x.x - bf2f(hh.x)); ll.y = f2bf(x.y - bf2f(hh.y));
    ll.z = f2bf(x.z - bf2f(hh.z)); ll.w = f2bf(x.w - bf2f(hh.w));
    ((ushort4*)dl)[loc] = ll;
  }
}

// ---------------------------------------------------------------------------
// bf16 MFMA GEMM on pre-split operands: C[m,n] = op( A[m,:]·B[n,:] + bias[n] )
// Ah/Al: MxK bf16 hi/lo rows; Bh/Bl: NxK. NSPLIT=3: hh+hl+lh; NSPLIT=1: hh.
// Tile 128x128, BK=32, 256 threads = 4 waves in 2x2 of 64x64 quadrants.
// MODE 0: f32 store  MODE 1: tanh + f32 store
// MODE 2: bf16 permuted store m=(v*SLEN+s), n=(h*32+d) ->
//         C[((v*8+h)*SLEN+s)*32+d]
// ---------------------------------------------------------------------------
template <int NSPLIT, int MODE>
__global__ __launch_bounds__(256) void gemmb_kernel(
    const unsigned short* __restrict__ Ah, const unsigned short* __restrict__ Al,
    const unsigned short* __restrict__ Bh, const unsigned short* __restrict__ Bl,
    const float* __restrict__ bias, void* __restrict__ Cv,
    int M, int N, int K) {
  __shared__ unsigned short LAh[128 * 32], LBh[128 * 32];
  __shared__ unsigned short LAl[NSPLIT > 1 ? 128 * 32 : 8];
  __shared__ unsigned short LBl[NSPLIT > 1 ? 128 * 32 : 8];

  const int tid = threadIdx.x;
  const int bm = blockIdx.y * 128, bn = blockIdx.x * 128;
  const int lane = tid & 63, w = tid >> 6;
  const int wm = (w & 1) * 64, wn = (w >> 1) * 64;
  const int l16 = lane & 15, quad = lane >> 4;

  // staging: 512 16B-chunks per array; thread t takes chunks {t, t+256}
  const int c0 = tid, c1 = tid + 256;
  const int r0 = c0 >> 2, s0 = (c0 & 3) * 8;
  const int r1 = c1 >> 2, s1 = (c1 & 3) * 8;
  const size_t a0 = (size_t)min(bm + r0, M - 1) * K + s0;
  const size_t a1 = (size_t)min(bm + r1, M - 1) * K + s1;
  const size_t b0o = (size_t)(bn + r0) * K + s0;
  const size_t b1o = (size_t)(bn + r1) * K + s1;
  const int l0 = c0 * 8, l1 = c1 * 8;

  f32x4 acc[4][4] = {};

  for (int k0 = 0; k0 < K; k0 += 32) {
    *(uint4*)&LAh[l0] = *(const uint4*)&Ah[a0 + k0];
    *(uint4*)&LAh[l1] = *(const uint4*)&Ah[a1 + k0];
    *(uint4*)&LBh[l0] = *(const uint4*)&Bh[b0o + k0];
    *(uint4*)&LBh[l1] = *(const uint4*)&Bh[b1o + k0];
    if constexpr (NSPLIT > 1) {
      *(uint4*)&LAl[l0] = *(const uint4*)&Al[a0 + k0];
      *(uint4*)&LAl[l1] = *(const uint4*)&Al[a1 + k0];
      *(uint4*)&LBl[l0] = *(const uint4*)&Bl[b0o + k0];
      *(uint4*)&LBl[l1] = *(const uint4*)&Bl[b1o + k0];
    }
    __syncthreads();

    short8 fah[4], fbh[4], fal[4], fbl[4];
#pragma unroll
    for (int i = 0; i < 4; ++i) {
      int ar = (wm + i * 16 + l16) * 32 + quad * 8;
      int br = (wn + i * 16 + l16) * 32 + quad * 8;
      fah[i] = *(const short8*)&LAh[ar];
      fbh[i] = *(const short8*)&LBh[br];
      if constexpr (NSPLIT > 1) {
        fal[i] = *(const short8*)&LAl[ar];
        fbl[i] = *(const short8*)&LBl[br];
      }
    }
#pragma unroll
    for (int i = 0; i < 4; ++i)
#pragma unroll
      for (int j = 0; j < 4; ++j) {
        acc[i][j] = __builtin_amdgcn_mfma_f32_16x16x32_bf16(fah[i], fbh[j], acc[i][j], 0, 0, 0);
        if constexpr (NSPLIT > 1) {
          acc[i][j] = __builtin_amdgcn_mfma_f32_16x16x32_bf16(fah[i], fbl[j], acc[i][j], 0, 0, 0);
          acc[i][j] = __builtin_amdgcn_mfma_f32_16x16x32_bf16(fal[i], fbh[j], acc[i][j], 0, 0, 0);
        }
      }
    __syncthreads();
  }

  // epilogue: C/D layout col(n)=lane&15, row(m)=quad*4+reg  [m89-verified]
#pragma unroll
  for (int j = 0; j < 4; ++j) {
    int n = bn + wn + j * 16 + l16;
    float bv = 0.f;
    if (MODE != 2 && bias) bv = bias[n];
#pragma unroll
    for (int i = 0; i < 4; ++i) {
      int mbase = bm + wm + i * 16 + quad * 4;
#pragma unroll
      for (int reg = 0; reg < 4; ++reg) {
        int m = mbase + reg;
        if (m >= M) continue;
        float c = acc[i][j][reg] + bv;
        if (MODE == 1) { float t = __expf(2.f * c); c = 1.f - 2.f / (t + 1.f); }
        if (MODE == 2) {
          int vv = m / SLENs;
          int s = m - vv * SLENs;
          int hh2 = n >> 5, dd = n & 31;
          ((unsigned short*)Cv)[((size_t)(vv * 8 + hh2) * SLENs + s) * 32 + dd] = f2bf(c);
        } else {
          ((float*)Cv)[(size_t)m * N + n] = c;
        }
      }
    }
  }
}

// ---------------------------------------------------------------------------
// Softmax over rows of 384 (one wave64 per row, 6 elems/lane).
// ---------------------------------------------------------------------------
__global__ __launch_bounds__(256) void softmax_kernel(float* __restrict__ attn) {
  int row = blockIdx.x * 4 + (threadIdx.x >> 6);
  int lane = threadIdx.x & 63;
  float* p = attn + (size_t)row * 384;
  float vals[6];
  float m = -1e30f;
#pragma unroll
  for (int i = 0; i < 6; ++i) { vals[i] = p[lane + i * 64]; m = fmaxf(m, vals[i]); }
#pragma unroll
  for (int off = 32; off > 0; off >>= 1) m = fmaxf(m, __shfl_xor(m, off, 64));
  float s = 0.f;
#pragma unroll
  for (int i = 0; i < 6; ++i) { vals[i] = __expf(vals[i] - m); s += vals[i]; }
#pragma unroll
  for (int off = 32; off > 0; off >>= 1) s += __shfl_xor(s, off, 64);
  float inv = 1.0f / s;
#pragma unroll
  for (int i = 0; i < 6; ++i) p[lane + i * 64] = vals[i] * inv;
}

// ---------------------------------------------------------------------------
// Per-sample records (SoA, 12B/rec):
//   rbase[i] = (start + y0*Wl + x0) << 6 | fx | fy<<1
//   rw[i]    = { bf(w01)<<16 | bf(w00),  bf(w11)<<16 | bf(w10) }
// where w00=(1-wx)(1-wy)w, w01=wx(1-wy)w, w10=(1-wx)wy w, w11=wx wy w.
// ---------------------------------------------------------------------------
__global__ __launch_bounds__(256) void precompute_kernel(
    const float* __restrict__ ref, const float* __restrict__ offs,
    const float* __restrict__ attn, int* __restrict__ rbase,
    uint2* __restrict__ rw) {
  int idx = blockIdx.x * 256 + threadIdx.x;   // < SAMP_TOT
  int q   = idx / A_ATTN;
  int rem = idx - q * A_ATTN;
  int v = (rem >> 6) % 6;
  int l = (rem >> 4) & 3;
  int z = rem & 3;

  float  w = attn[idx];
  float2 o = ((const float2*)offs)[idx];
  const float* rp = ref + ((size_t)((q * 6 + v) * 4 + l) * 4 + z) * 2;
  float rx = rp[0], ry = rp[1];

  int Wl = 64 >> l;
  int start = (l == 0) ? 0 : (l == 1 ? 4096 : (l == 2 ? 5120 : 5376));
  float sc = 0.5f * (float)(Wl - 1);

  float x = fminf(1.f, fmaxf(-1.f, rx + o.x));
  float y = fminf(1.f, fmaxf(-1.f, ry + o.y));
  float xp = (x + 1.f) * sc;
  float yp = (y + 1.f) * sc;
  float x0f = floorf(xp), y0f = floorf(yp);
  int x0 = (int)x0f, y0 = (int)y0f;
  float wx = xp - x0f, wy = yp - y0f;
  int fx = (x0 + 1 < Wl) ? 1 : 0;
  int fy = (y0 + 1 < Wl) ? 2 : 0;

  float wxw = wx * w, wmx = w - wxw;
  float w01 = wxw * (1.f - wy), w11 = wxw * wy;
  float w00 = wmx * (1.f - wy), w10 = wmx * wy;

  rbase[idx] = ((start + y0 * Wl + x0) << 6) | fx | fy;
  rw[idx] = make_uint2(((unsigned)f2bf(w01) << 16) | f2bf(w00),
                       ((unsigned)f2bf(w11) << 16) | f2bf(w10));
}

// ---------------------------------------------------------------------------
// Sampling v3: wave = one (q,h). lane bits: [1:0]=e (channel oct, 16B),
// [2]=cx, [3]=cy, [5:4]=r (4 records per wave-iteration).
// Each lane: one 16B gather (8 bf16 channels of its corner of its record),
// packed-bf16 corner weight, 8 fma. Butterfly over bits 2..5.
// Writes out_pre as bf16 hi+lo (feeds NSPLIT=3 final GEMM).
// blockIdx&7 = h -> XCD L2 affinity (6 slices ~2.1MB per XCD).
// ---------------------------------------------------------------------------
__global__ __launch_bounds__(256) void sample_kernel(
    const int* __restrict__ rbase, const uint2* __restrict__ rw,
    const unsigned short* __restrict__ val_t,
    unsigned short* __restrict__ oph, unsigned short* __restrict__ opl) {
  const int h  = blockIdx.x & 7;
  const int qt = blockIdx.x >> 3;
  const int lane = threadIdx.x & 63;
  const int q  = qt * 4 + (threadIdx.x >> 6);

  const int e16 = (lane & 3) << 4;
  const int cxm = ((lane >> 2) & 1) << 6;   // 0 or 64
  const bool cy = (lane >> 3) & 1;
  const int r   = lane >> 4;

  const int rb0 = q * A_ATTN + h * 384 + r;
  const int*  rb  = rbase + rb0;
  const uint2* rwp = rw + rb0;

  float acc[8] = {};
  int ib = 0;

#pragma unroll
  for (int v = 0; v < 6; ++v) {
    const char* sb = (const char*)val_t + (size_t)(v * 8 + h) * (SLENs * 64);
#pragma unroll
    for (int l = 0; l < 4; ++l) {
      const int cym = cy ? (2 << (11 - l)) : 0;   // fy-gated row stride mask
#pragma unroll
      for (int i = 0; i < 4; ++i) {
        int bf = rb[ib];
        uint2 pk2 = rwp[ib];
        ib += 4;
        int voff = ((bf & -64) | e16) + ((bf << 6) & cxm) + ((bf << (11 - l)) & cym);
        uint4 u = *(const uint4*)(sb + voff);
        unsigned int pk = cy ? pk2.y : pk2.x;
        float wl_ = __uint_as_float(cxm ? (pk & 0xFFFF0000u) : (pk << 16));
        acc[0] = fmaf(wl_, __uint_as_float(u.x << 16),          acc[0]);
        acc[1] = fmaf(wl_, __uint_as_float(u.x & 0xFFFF0000u),  acc[1]);
        acc[2] = fmaf(wl_, __uint_as_float(u.y << 16),          acc[2]);
        acc[3] = fmaf(wl_, __uint_as_float(u.y & 0xFFFF0000u),  acc[3]);
        acc[4] = fmaf(wl_, __uint_as_float(u.z << 16),          acc[4]);
        acc[5] = fmaf(wl_, __uint_as_float(u.z & 0xFFFF0000u),  acc[5]);
        acc[6] = fmaf(wl_, __uint_as_float(u.w << 16),          acc[6]);
        acc[7] = fmaf(wl_, __uint_as_float(u.w & 0xFFFF0000u),  acc[7]);
      }
    }
  }

#pragma unroll
  for (int m = 4; m <= 32; m <<= 1)
#pragma unroll
    for (int j = 0; j < 8; ++j) acc[j] += __shfl_xor(acc[j], m, 64);

  if (lane < 4) {
    int off = q * EMB + h * 32 + lane * 8;   // channel oct e = lane
    ushort4 h0, h1, lo0, lo1;
    h0.x = f2bf(acc[0]); h0.y = f2bf(acc[1]); h0.z = f2bf(acc[2]); h0.w = f2bf(acc[3]);
    h1.x = f2bf(acc[4]); h1.y = f2bf(acc[5]); h1.z = f2bf(acc[6]); h1.w = f2bf(acc[7]);
    lo0.x = f2bf(acc[0] - bf2f(h0.x)); lo0.y = f2bf(acc[1] - bf2f(h0.y));
    lo0.z = f2bf(acc[2] - bf2f(h0.z)); lo0.w = f2bf(acc[3] - bf2f(h0.w));
    lo1.x = f2bf(acc[4] - bf2f(h1.x)); lo1.y = f2bf(acc[5] - bf2f(h1.y));
    lo1.z = f2bf(acc[6] - bf2f(h1.z)); lo1.w = f2bf(acc[7] - bf2f(h1.w));
    *(ushort4*)&oph[off] = h0;  *(ushort4*)&oph[off + 4] = h1;
    *(ushort4*)&opl[off] = lo0; *(ushort4*)&opl[off + 4] = lo1;
  }
}

// ---------------------------------------------------------------------------
extern "C" void kernel_launch(void* const* d_in, const int* in_sizes, int n_in,
                              void* d_out, int out_size, void* d_ws, size_t ws_size,
                              hipStream_t stream) {
  const float* queries    = (const float*)d_in[0];
  const float* ref_points = (const float*)d_in[1];
  const float* value      = (const float*)d_in[2];
  const float* Wv    = (const float*)d_in[4];
  const float* Woff  = (const float*)d_in[5];
  const float* boff  = (const float*)d_in[6];
  const float* Wattn = (const float*)d_in[7];
  const float* battn = (const float*)d_in[8];
  const float* Wout  = (const float*)d_in[9];
  float* out = (float*)d_out;

  // ws layout, byte offsets (peak 155.06 MB < round-2-proven 155.98 MB).
  // W-split arrays for Woff/Wattn overlay the rec region (dead before
  // precompute writes rbase/rw).
  char* W = (char*)d_ws;
  float* offs            = (float*)(W + 0);                  // 39,321,600
  float* attn            = (float*)(W + 39321600);           // 19,660,800
  unsigned short* val_t  = (unsigned short*)(W + 58982400);  // 16,711,680
  unsigned short* qh     = (unsigned short*)(W + 75694080);  //    819,200
  unsigned short* ql     = (unsigned short*)(W + 76513280);  //    819,200
  unsigned short* vh     = (unsigned short*)(W + 77332480);  // 16,711,680
  unsigned short* Wvh    = (unsigned short*)(W + 94044160);  //    131,072
  unsigned short* Wouth  = (unsigned short*)(W + 94175232);  //    131,072
  unsigned short* Woutl  = (unsigned short*)(W + 94306304);  //    131,072
  unsigned short* oph    = (unsigned short*)(W + 94437376);  //    819,200
  unsigned short* opl    = (unsigned short*)(W + 95256576);  //    819,200
  int*   rbase           = (int*)(W + 96075776);             // 19,660,800
  uint2* rw              = (uint2*)(W + 115736576);          // 39,321,600 -> ends 155,058,176
  unsigned short* Woffh  = (unsigned short*)(W + 96075776);  // overlay (dead after offs GEMM)
  unsigned short* Woffl  = (unsigned short*)(W + 99221504);
  unsigned short* Wattnh = (unsigned short*)(W + 102367232);
  unsigned short* Wattnl = (unsigned short*)(W + 103940096);

  dim3 blk(256);

  // 1. split all GEMM operands to bf16 hi(/lo)
  split_all_kernel<<<10992, blk, 0, stream>>>(
      queries, value, Woff, Wattn, Wv, Wout,
      qh, ql, vh, Woffh, Woffl, Wattnh, Wattnl, Wvh, Wouth, Woutl);
  // 2. offs = tanh(q @ Woff.T + boff)
  gemmb_kernel<3, 1><<<dim3(A_OFF / 128, (QQ + 127) / 128), blk, 0, stream>>>(
      qh, ql, Woffh, Woffl, boff, offs, QQ, A_OFF, EMB);
  // 3. attn_raw = q @ Wattn.T + battn
  gemmb_kernel<3, 0><<<dim3(A_ATTN / 128, (QQ + 127) / 128), blk, 0, stream>>>(
      qh, ql, Wattnh, Wattnl, battn, attn, QQ, A_ATTN, EMB);
  // 4. softmax per (q,h) over 384
  softmax_kernel<<<(QQ * NHh) / 4, blk, 0, stream>>>(attn);
  // 5. val_t (bf16, [v][h][s][d]) = (value @ Wv.T) permuted — hi-only inputs
  gemmb_kernel<1, 2><<<dim3(EMB / 128, (NVv * SLENs) / 128), blk, 0, stream>>>(
      vh, nullptr, Wvh, nullptr, nullptr, val_t, NVv * SLENs, EMB, EMB);
  // 6. per-sample records (overwrites the Woff/Wattn splits — now dead)
  precompute_kernel<<<SAMP_TOT / 256, blk, 0, stream>>>(
      ref_points, offs, attn, rbase, rw);
  // 7. bilinear sampling + weighted accumulation -> out_pre bf16 hi/lo
  sample_kernel<<<QQ * NHh / 4, blk, 0, stream>>>(rbase, rw, val_t, oph, opl);
  // 8. out = out_pre @ Wout.T
  gemmb_kernel<3, 0><<<dim3(EMB / 128, (QQ + 127) / 128), blk, 0, stream>>>(
      oph, opl, Wouth, Woutl, nullptr, out, QQ, EMB, EMB);
}

// Round 7
// 323.741 us; speedup vs baseline: 4.2864x; 4.2864x over previous
//
#include <hip/hip_runtime.h>
#include <hip/hip_bf16.h>
#include <math.h>

#define NHh   8
#define EMB   256
#define HDd   32
#define NVv   6
#define SLENs 5440
#define QQ    1600
#define A_ATTN 3072   // NH*NV*NL*NP*NZ
#define A_OFF  6144
#define SAMP_TOT (QQ * A_ATTN)   // 4,915,200

typedef __attribute__((ext_vector_type(8))) short short8;
typedef __attribute__((ext_vector_type(4))) float f32x4;

__device__ __forceinline__ unsigned short f2bf(float f) {
  __hip_bfloat16 h = __float2bfloat16(f);
  return *(unsigned short*)&h;
}
__device__ __forceinline__ float bf2f(unsigned short u) {
  return __uint_as_float((unsigned int)u << 16);
}

// ---------------------------------------------------------------------------
// One-shot fp32 -> bf16 hi(/lo) split of all GEMM operands.
// ---------------------------------------------------------------------------
__global__ __launch_bounds__(256) void split_all_kernel(
    const float* __restrict__ q, const float* __restrict__ value,
    const float* __restrict__ Woff, const float* __restrict__ Wattn,
    const float* __restrict__ Wv, const float* __restrict__ Wout,
    unsigned short* __restrict__ qh, unsigned short* __restrict__ ql,
    unsigned short* __restrict__ vh,
    unsigned short* __restrict__ Woffh, unsigned short* __restrict__ Woffl,
    unsigned short* __restrict__ Wattnh, unsigned short* __restrict__ Wattnl,
    unsigned short* __restrict__ Wvh,
    unsigned short* __restrict__ Wouth, unsigned short* __restrict__ Woutl) {
  int i4 = blockIdx.x * 256 + threadIdx.x;   // < 2,813,952
  const float* src; unsigned short* dh; unsigned short* dl; int loc;
  if      (i4 < 102400)  { src = q;     dh = qh;     dl = ql;     loc = i4; }
  else if (i4 < 2191360) { src = value; dh = vh;     dl = nullptr; loc = i4 - 102400; }
  else if (i4 < 2584576) { src = Woff;  dh = Woffh;  dl = Woffl;  loc = i4 - 2191360; }
  else if (i4 < 2781184) { src = Wattn; dh = Wattnh; dl = Wattnl; loc = i4 - 2584576; }
  else if (i4 < 2797568) { src = Wv;    dh = Wvh;    dl = nullptr; loc = i4 - 2781184; }
  else                   { src = Wout;  dh = Wouth;  dl = Woutl;  loc = i4 - 2797568; }
  float4 x = ((const float4*)src)[loc];
  ushort4 hh;
  hh.x = f2bf(x.x); hh.y = f2bf(x.y); hh.z = f2bf(x.z); hh.w = f2bf(x.w);
  ((ushort4*)dh)[loc] = hh;
  if (dl) {
    ushort4 ll;
    ll.x = f2bf(x.x - bf2f(hh.x)); ll.y = f2bf(x.y - bf2f(hh.y));
    ll.z = f2bf(x.z - bf2f(hh.z)); ll.w = f2bf(x.w - bf2f(hh.w));
    ((ushort4*)dl)[loc] = ll;
  }
}

// ---------------------------------------------------------------------------
// bf16 MFMA GEMM on pre-split operands: C[m,n] = op( A[m,:]·B[n,:] + bias[n] )
// NSPLIT=3: hh+hl+lh; NSPLIT=1: hh. Tile 128x128, BK=32, 4 waves 2x2.
// MODE 0: f32 store  MODE 1: tanh + f32 store  MODE 2: bf16 permuted store.
// ---------------------------------------------------------------------------
template <int NSPLIT, int MODE>
__global__ __launch_bounds__(256) void gemmb_kernel(
    const unsigned short* __restrict__ Ah, const unsigned short* __restrict__ Al,
    const unsigned short* __restrict__ Bh, const unsigned short* __restrict__ Bl,
    const float* __restrict__ bias, void* __restrict__ Cv,
    int M, int N, int K) {
  __shared__ unsigned short LAh[128 * 32], LBh[128 * 32];
  __shared__ unsigned short LAl[NSPLIT > 1 ? 128 * 32 : 8];
  __shared__ unsigned short LBl[NSPLIT > 1 ? 128 * 32 : 8];

  const int tid = threadIdx.x;
  const int bm = blockIdx.y * 128, bn = blockIdx.x * 128;
  const int lane = tid & 63, w = tid >> 6;
  const int wm = (w & 1) * 64, wn = (w >> 1) * 64;
  const int l16 = lane & 15, quad = lane >> 4;

  const int c0 = tid, c1 = tid + 256;
  const int r0 = c0 >> 2, s0 = (c0 & 3) * 8;
  const int r1 = c1 >> 2, s1 = (c1 & 3) * 8;
  const size_t a0 = (size_t)min(bm + r0, M - 1) * K + s0;
  const size_t a1 = (size_t)min(bm + r1, M - 1) * K + s1;
  const size_t b0o = (size_t)(bn + r0) * K + s0;
  const size_t b1o = (size_t)(bn + r1) * K + s1;
  const int l0 = c0 * 8, l1 = c1 * 8;

  f32x4 acc[4][4] = {};

  for (int k0 = 0; k0 < K; k0 += 32) {
    *(uint4*)&LAh[l0] = *(const uint4*)&Ah[a0 + k0];
    *(uint4*)&LAh[l1] = *(const uint4*)&Ah[a1 + k0];
    *(uint4*)&LBh[l0] = *(const uint4*)&Bh[b0o + k0];
    *(uint4*)&LBh[l1] = *(const uint4*)&Bh[b1o + k0];
    if constexpr (NSPLIT > 1) {
      *(uint4*)&LAl[l0] = *(const uint4*)&Al[a0 + k0];
      *(uint4*)&LAl[l1] = *(const uint4*)&Al[a1 + k0];
      *(uint4*)&LBl[l0] = *(const uint4*)&Bl[b0o + k0];
      *(uint4*)&LBl[l1] = *(const uint4*)&Bl[b1o + k0];
    }
    __syncthreads();

    short8 fah[4], fbh[4], fal[4], fbl[4];
#pragma unroll
    for (int i = 0; i < 4; ++i) {
      int ar = (wm + i * 16 + l16) * 32 + quad * 8;
      int br = (wn + i * 16 + l16) * 32 + quad * 8;
      fah[i] = *(const short8*)&LAh[ar];
      fbh[i] = *(const short8*)&LBh[br];
      if constexpr (NSPLIT > 1) {
        fal[i] = *(const short8*)&LAl[ar];
        fbl[i] = *(const short8*)&LBl[br];
      }
    }
#pragma unroll
    for (int i = 0; i < 4; ++i)
#pragma unroll
      for (int j = 0; j < 4; ++j) {
        acc[i][j] = __builtin_amdgcn_mfma_f32_16x16x32_bf16(fah[i], fbh[j], acc[i][j], 0, 0, 0);
        if constexpr (NSPLIT > 1) {
          acc[i][j] = __builtin_amdgcn_mfma_f32_16x16x32_bf16(fah[i], fbl[j], acc[i][j], 0, 0, 0);
          acc[i][j] = __builtin_amdgcn_mfma_f32_16x16x32_bf16(fal[i], fbh[j], acc[i][j], 0, 0, 0);
        }
      }
    __syncthreads();
  }

  // epilogue: C/D layout col(n)=lane&15, row(m)=quad*4+reg  [m89-verified]
#pragma unroll
  for (int j = 0; j < 4; ++j) {
    int n = bn + wn + j * 16 + l16;
    float bv = 0.f;
    if (MODE != 2 && bias) bv = bias[n];
#pragma unroll
    for (int i = 0; i < 4; ++i) {
      int mbase = bm + wm + i * 16 + quad * 4;
#pragma unroll
      for (int reg = 0; reg < 4; ++reg) {
        int m = mbase + reg;
        if (m >= M) continue;
        float c = acc[i][j][reg] + bv;
        if (MODE == 1) { float t = __expf(2.f * c); c = 1.f - 2.f / (t + 1.f); }
        if (MODE == 2) {
          int vv = m / SLENs;
          int s = m - vv * SLENs;
          int hh2 = n >> 5, dd = n & 31;
          ((unsigned short*)Cv)[((size_t)(vv * 8 + hh2) * SLENs + s) * 32 + dd] = f2bf(c);
        } else {
          ((float*)Cv)[(size_t)m * N + n] = c;
        }
      }
    }
  }
}

// ---------------------------------------------------------------------------
// Softmax over rows of 384 (one wave64 per row, 6 elems/lane).
// ---------------------------------------------------------------------------
__global__ __launch_bounds__(256) void softmax_kernel(float* __restrict__ attn) {
  int row = blockIdx.x * 4 + (threadIdx.x >> 6);
  int lane = threadIdx.x & 63;
  float* p = attn + (size_t)row * 384;
  float vals[6];
  float m = -1e30f;
#pragma unroll
  for (int i = 0; i < 6; ++i) { vals[i] = p[lane + i * 64]; m = fmaxf(m, vals[i]); }
#pragma unroll
  for (int off = 32; off > 0; off >>= 1) m = fmaxf(m, __shfl_xor(m, off, 64));
  float s = 0.f;
#pragma unroll
  for (int i = 0; i < 6; ++i) { vals[i] = __expf(vals[i] - m); s += vals[i]; }
#pragma unroll
  for (int off = 32; off > 0; off >>= 1) s += __shfl_xor(s, off, 64);
  float inv = 1.0f / s;
#pragma unroll
  for (int i = 0; i < 6; ++i) p[lane + i * 64] = vals[i] * inv;
}

// ---------------------------------------------------------------------------
// Per-sample records (SoA, 12B/rec):
//   rbase[i] = (start + y0*Wl + x0) << 6 | fx | fy<<1
//   rw[i]    = { bf(w01)<<16 | bf(w00),  bf(w11)<<16 | bf(w10) }
// ---------------------------------------------------------------------------
__global__ __launch_bounds__(256) void precompute_kernel(
    const float* __restrict__ ref, const float* __restrict__ offs,
    const float* __restrict__ attn, int* __restrict__ rbase,
    uint2* __restrict__ rw) {
  int idx = blockIdx.x * 256 + threadIdx.x;   // < SAMP_TOT
  int q   = idx / A_ATTN;
  int rem = idx - q * A_ATTN;
  int v = (rem >> 6) % 6;
  int l = (rem >> 4) & 3;
  int z = rem & 3;

  float  w = attn[idx];
  float2 o = ((const float2*)offs)[idx];
  const float* rp = ref + ((size_t)((q * 6 + v) * 4 + l) * 4 + z) * 2;
  float rx = rp[0], ry = rp[1];

  int Wl = 64 >> l;
  int start = (l == 0) ? 0 : (l == 1 ? 4096 : (l == 2 ? 5120 : 5376));
  float sc = 0.5f * (float)(Wl - 1);

  float x = fminf(1.f, fmaxf(-1.f, rx + o.x));
  float y = fminf(1.f, fmaxf(-1.f, ry + o.y));
  float xp = (x + 1.f) * sc;
  float yp = (y + 1.f) * sc;
  float x0f = floorf(xp), y0f = floorf(yp);
  int x0 = (int)x0f, y0 = (int)y0f;
  float wx = xp - x0f, wy = yp - y0f;
  int fx = (x0 + 1 < Wl) ? 1 : 0;
  int fy = (y0 + 1 < Wl) ? 2 : 0;

  float wxw = wx * w, wmx = w - wxw;
  float w01 = wxw * (1.f - wy), w11 = wxw * wy;
  float w00 = wmx * (1.f - wy), w10 = wmx * wy;

  rbase[idx] = ((start + y0 * Wl + x0) << 6) | fx | fy;
  rw[idx] = make_uint2(((unsigned)f2bf(w01) << 16) | f2bf(w00),
                       ((unsigned)f2bf(w11) << 16) | f2bf(w10));
}

// ---------------------------------------------------------------------------
// Sampling v3c: wave = one (q,h). lane bits: [1:0]=e (channel oct, 16B),
// [2]=cx, [3]=cy, [5:4]=r (4 records per wave-iteration).
// UNROLL POLICY (round-5 lesson): v/l loops at unroll 1 — full 96-body
// unroll hoisted 96 record loads -> 256 VGPR -> scratch spill.
// INDEXING (round-6 lesson): lane r's consecutive records are spaced 4
// apart (records i*4 + r within each 16-record l-chunk) — stride is i*4,
// NOT i. rb is already offset by r.
// ---------------------------------------------------------------------------
__global__ __launch_bounds__(256) void sample_kernel(
    const int* __restrict__ rbase, const uint2* __restrict__ rw,
    const unsigned short* __restrict__ val_t,
    unsigned short* __restrict__ oph, unsigned short* __restrict__ opl) {
  const int h  = blockIdx.x & 7;
  const int qt = blockIdx.x >> 3;
  const int lane = threadIdx.x & 63;
  const int q  = qt * 4 + (threadIdx.x >> 6);

  const int e16 = (lane & 3) << 4;
  const int cxm = ((lane >> 2) & 1) << 6;   // 0 or 64
  const bool cy = (lane >> 3) & 1;
  const int r   = lane >> 4;

  const int rb0 = q * A_ATTN + h * 384 + r;
  const int*  rb  = rbase + rb0;
  const uint2* rwp = rw + rb0;

  float acc[8] = {};
  int ib = 0;

#pragma unroll 1
  for (int v = 0; v < 6; ++v) {
    const char* sb = (const char*)val_t + (size_t)(v * 8 + h) * (SLENs * 64);
#pragma unroll 1
    for (int l = 0; l < 4; ++l) {
      const int cym = cy ? (2 << (11 - l)) : 0;   // fy-gated row stride mask
#pragma unroll
      for (int i = 0; i < 4; ++i) {
        int ri = ib + i * 4;            // lane r's records: r + ib + 4i
        int bf = rb[ri];
        uint2 pk2 = rwp[ri];
        int voff = ((bf & -64) | e16) + ((bf << 6) & cxm) + ((bf << (11 - l)) & cym);
        uint4 u = *(const uint4*)(sb + voff);
        unsigned int pk = cy ? pk2.y : pk2.x;
        float wl_ = __uint_as_float(cxm ? (pk & 0xFFFF0000u) : (pk << 16));
        acc[0] = fmaf(wl_, __uint_as_float(u.x << 16),          acc[0]);
        acc[1] = fmaf(wl_, __uint_as_float(u.x & 0xFFFF0000u),  acc[1]);
        acc[2] = fmaf(wl_, __uint_as_float(u.y << 16),          acc[2]);
        acc[3] = fmaf(wl_, __uint_as_float(u.y & 0xFFFF0000u),  acc[3]);
        acc[4] = fmaf(wl_, __uint_as_float(u.z << 16),          acc[4]);
        acc[5] = fmaf(wl_, __uint_as_float(u.z & 0xFFFF0000u),  acc[5]);
        acc[6] = fmaf(wl_, __uint_as_float(u.w << 16),          acc[6]);
        acc[7] = fmaf(wl_, __uint_as_float(u.w & 0xFFFF0000u),  acc[7]);
      }
      ib += 16;
    }
  }

#pragma unroll
  for (int m = 4; m <= 32; m <<= 1)
#pragma unroll
    for (int j = 0; j < 8; ++j) acc[j] += __shfl_xor(acc[j], m, 64);

  if (lane < 4) {
    int off = q * EMB + h * 32 + lane * 8;   // channel oct e = lane
    ushort4 h0, h1, lo0, lo1;
    h0.x = f2bf(acc[0]); h0.y = f2bf(acc[1]); h0.z = f2bf(acc[2]); h0.w = f2bf(acc[3]);
    h1.x = f2bf(acc[4]); h1.y = f2bf(acc[5]); h1.z = f2bf(acc[6]); h1.w = f2bf(acc[7]);
    lo0.x = f2bf(acc[0] - bf2f(h0.x)); lo0.y = f2bf(acc[1] - bf2f(h0.y));
    lo0.z = f2bf(acc[2] - bf2f(h0.z)); lo0.w = f2bf(acc[3] - bf2f(h0.w));
    lo1.x = f2bf(acc[4] - bf2f(h1.x)); lo1.y = f2bf(acc[5] - bf2f(h1.y));
    lo1.z = f2bf(acc[6] - bf2f(h1.z)); lo1.w = f2bf(acc[7] - bf2f(h1.w));
    *(ushort4*)&oph[off] = h0;  *(ushort4*)&oph[off + 4] = h1;
    *(ushort4*)&opl[off] = lo0; *(ushort4*)&opl[off + 4] = lo1;
  }
}

// ---------------------------------------------------------------------------
extern "C" void kernel_launch(void* const* d_in, const int* in_sizes, int n_in,
                              void* d_out, int out_size, void* d_ws, size_t ws_size,
                              hipStream_t stream) {
  const float* queries    = (const float*)d_in[0];
  const float* ref_points = (const float*)d_in[1];
  const float* value      = (const float*)d_in[2];
  const float* Wv    = (const float*)d_in[4];
  const float* Woff  = (const float*)d_in[5];
  const float* boff  = (const float*)d_in[6];
  const float* Wattn = (const float*)d_in[7];
  const float* battn = (const float*)d_in[8];
  const float* Wout  = (const float*)d_in[9];
  float* out = (float*)d_out;

  // ws layout, byte offsets (peak 155.06 MB, proven fit).
  char* W = (char*)d_ws;
  float* offs            = (float*)(W + 0);                  // 39,321,600
  float* attn            = (float*)(W + 39321600);           // 19,660,800
  unsigned short* val_t  = (unsigned short*)(W + 58982400);  // 16,711,680
  unsigned short* qh     = (unsigned short*)(W + 75694080);  //    819,200
  unsigned short* ql     = (unsigned short*)(W + 76513280);  //    819,200
  unsigned short* vh     = (unsigned short*)(W + 77332480);  // 16,711,680
  unsigned short* Wvh    = (unsigned short*)(W + 94044160);  //    131,072
  unsigned short* Wouth  = (unsigned short*)(W + 94175232);  //    131,072
  unsigned short* Woutl  = (unsigned short*)(W + 94306304);  //    131,072
  unsigned short* oph    = (unsigned short*)(W + 94437376);  //    819,200
  unsigned short* opl    = (unsigned short*)(W + 95256576);  //    819,200
  int*   rbase           = (int*)(W + 96075776);             // 19,660,800
  uint2* rw              = (uint2*)(W + 115736576);          // 39,321,600 -> ends 155,058,176
  unsigned short* Woffh  = (unsigned short*)(W + 96075776);  // overlay (dead after offs GEMM)
  unsigned short* Woffl  = (unsigned short*)(W + 99221504);
  unsigned short* Wattnh = (unsigned short*)(W + 102367232);
  unsigned short* Wattnl = (unsigned short*)(W + 103940096);

  dim3 blk(256);

  // 1. split all GEMM operands to bf16 hi(/lo)
  split_all_kernel<<<10992, blk, 0, stream>>>(
      queries, value, Woff, Wattn, Wv, Wout,
      qh, ql, vh, Woffh, Woffl, Wattnh, Wattnl, Wvh, Wouth, Woutl);
  // 2. offs = tanh(q @ Woff.T + boff)
  gemmb_kernel<3, 1><<<dim3(A_OFF / 128, (QQ + 127) / 128), blk, 0, stream>>>(
      qh, ql, Woffh, Woffl, boff, offs, QQ, A_OFF, EMB);
  // 3. attn_raw = q @ Wattn.T + battn
  gemmb_kernel<3, 0><<<dim3(A_ATTN / 128, (QQ + 127) / 128), blk, 0, stream>>>(
      qh, ql, Wattnh, Wattnl, battn, attn, QQ, A_ATTN, EMB);
  // 4. softmax per (q,h) over 384
  softmax_kernel<<<(QQ * NHh) / 4, blk, 0, stream>>>(attn);
  // 5. val_t (bf16, [v][h][s][d]) = (value @ Wv.T) permuted — hi-only inputs
  gemmb_kernel<1, 2><<<dim3(EMB / 128, (NVv * SLENs) / 128), blk, 0, stream>>>(
      vh, nullptr, Wvh, nullptr, nullptr, val_t, NVv * SLENs, EMB, EMB);
  // 6. per-sample records (overwrites the Woff/Wattn splits — now dead)
  precompute_kernel<<<SAMP_TOT / 256, blk, 0, stream>>>(
      ref_points, offs, attn, rbase, rw);
  // 7. bilinear sampling + weighted accumulation -> out_pre bf16 hi/lo
  sample_kernel<<<QQ * NHh / 4, blk, 0, stream>>>(rbase, rw, val_t, oph, opl);
  // 8. out = out_pre @ Wout.T
  gemmb_kernel<3, 0><<<dim3(EMB / 128, (QQ + 127) / 128), blk, 0, stream>>>(
      oph, opl, Wouth, Woutl, nullptr, out, QQ, EMB, EMB);
}

// Round 8
// 294.218 us; speedup vs baseline: 4.7165x; 1.1003x over previous
//
#include <hip/hip_runtime.h>
#include <hip/hip_bf16.h>
#include <math.h>

#define NHh   8
#define EMB   256
#define HDd   32
#define NVv   6
#define SLENs 5440
#define QQ    1600
#define A_ATTN 3072   // NH*NV*NL*NP*NZ
#define A_OFF  6144
#define SAMP_TOT (QQ * A_ATTN)   // 4,915,200

typedef __attribute__((ext_vector_type(8))) short short8;
typedef __attribute__((ext_vector_type(4))) float f32x4;

__device__ __forceinline__ unsigned short f2bf(float f) {
  __hip_bfloat16 h = __float2bfloat16(f);
  return *(unsigned short*)&h;
}
__device__ __forceinline__ float bf2f(unsigned short u) {
  return __uint_as_float((unsigned int)u << 16);
}

// async global->LDS DMA, 16B per lane. LDS dest semantics: wave-uniform base
// + lane*16 (m104/m108) — caller must pass lane-ordered contiguous LDS addrs.
__device__ __forceinline__ void dma16(const unsigned short* g, unsigned short* l) {
  __builtin_amdgcn_global_load_lds(
      (const __attribute__((address_space(1))) unsigned int*)g,
      (__attribute__((address_space(3))) unsigned int*)l, 16, 0, 0);
}

// ---------------------------------------------------------------------------
// One-shot fp32 -> bf16 hi(/lo) split of all GEMM operands.
// ---------------------------------------------------------------------------
__global__ __launch_bounds__(256) void split_all_kernel(
    const float* __restrict__ q, const float* __restrict__ value,
    const float* __restrict__ Woff, const float* __restrict__ Wattn,
    const float* __restrict__ Wv, const float* __restrict__ Wout,
    unsigned short* __restrict__ qh, unsigned short* __restrict__ ql,
    unsigned short* __restrict__ vh,
    unsigned short* __restrict__ Woffh, unsigned short* __restrict__ Woffl,
    unsigned short* __restrict__ Wattnh, unsigned short* __restrict__ Wattnl,
    unsigned short* __restrict__ Wvh,
    unsigned short* __restrict__ Wouth, unsigned short* __restrict__ Woutl) {
  int i4 = blockIdx.x * 256 + threadIdx.x;   // < 2,813,952
  const float* src; unsigned short* dh; unsigned short* dl; int loc;
  if      (i4 < 102400)  { src = q;     dh = qh;     dl = ql;     loc = i4; }
  else if (i4 < 2191360) { src = value; dh = vh;     dl = nullptr; loc = i4 - 102400; }
  else if (i4 < 2584576) { src = Woff;  dh = Woffh;  dl = Woffl;  loc = i4 - 2191360; }
  else if (i4 < 2781184) { src = Wattn; dh = Wattnh; dl = Wattnl; loc = i4 - 2584576; }
  else if (i4 < 2797568) { src = Wv;    dh = Wvh;    dl = nullptr; loc = i4 - 2781184; }
  else                   { src = Wout;  dh = Wouth;  dl = Woutl;  loc = i4 - 2797568; }
  float4 x = ((const float4*)src)[loc];
  ushort4 hh;
  hh.x = f2bf(x.x); hh.y = f2bf(x.y); hh.z = f2bf(x.z); hh.w = f2bf(x.w);
  ((ushort4*)dh)[loc] = hh;
  if (dl) {
    ushort4 ll;
    ll.x = f2bf(x.x - bf2f(hh.x)); ll.y = f2bf(x.y - bf2f(hh.y));
    ll.z = f2bf(x.z - bf2f(hh.z)); ll.w = f2bf(x.w - bf2f(hh.w));
    ((ushort4*)dl)[loc] = ll;
  }
}

// ---------------------------------------------------------------------------
// bf16 MFMA GEMM on pre-split operands, global_load_lds staging.
// NSPLIT=3: hh+hl+lh; NSPLIT=1: hh. Tile 128x128, BK=32, 4 waves 2x2.
// MODE 0: f32 store to Cv (+bias if non-null)
// MODE 2: bf16 permuted store (val): m=(v*SLEN+s), n=(h*32+d)
// MODE 3: fused offs/attn: n<A_OFF -> tanh(c+bias[n]) into Cv (stride A_OFF);
//         else c+bias2[n-A_OFF] into Cv2 (stride A_ATTN). 128-tiles never
//         straddle n=6144 (6144/128=48) so the branch is block-uniform.
// ---------------------------------------------------------------------------
template <int NSPLIT, int MODE>
__global__ __launch_bounds__(256) void gemmb_kernel(
    const unsigned short* __restrict__ Ah, const unsigned short* __restrict__ Al,
    const unsigned short* __restrict__ Bh, const unsigned short* __restrict__ Bl,
    const float* __restrict__ bias, const float* __restrict__ bias2,
    void* __restrict__ Cv, void* __restrict__ Cv2,
    int M, int N, int K) {
  __shared__ unsigned short LAh[128 * 32], LBh[128 * 32];
  __shared__ unsigned short LAl[NSPLIT > 1 ? 128 * 32 : 8];
  __shared__ unsigned short LBl[NSPLIT > 1 ? 128 * 32 : 8];

  const int tid = threadIdx.x;
  const int bm = blockIdx.y * 128, bn = blockIdx.x * 128;
  const int lane = tid & 63, w = tid >> 6;
  const int wm = (w & 1) * 64, wn = (w >> 1) * 64;
  const int l16 = lane & 15, quad = lane >> 4;

  // staging: 512 16B chunks per array; chunk c -> row c>>2, kcol (c&3)*8,
  // LDS byte off c*16 (lane-ordered: c = 64*wave + lane, then +256).
  const int c0 = tid, c1 = tid + 256;
  const int r0 = c0 >> 2, s0 = (c0 & 3) * 8;
  const int r1 = c1 >> 2, s1 = (c1 & 3) * 8;
  const size_t a0 = (size_t)min(bm + r0, M - 1) * K + s0;
  const size_t a1 = (size_t)min(bm + r1, M - 1) * K + s1;
  const size_t b0o = (size_t)(bn + r0) * K + s0;
  const size_t b1o = (size_t)(bn + r1) * K + s1;
  const int l0 = c0 * 8, l1 = c1 * 8;

  f32x4 acc[4][4] = {};

  for (int k0 = 0; k0 < K; k0 += 32) {
    dma16(&Ah[a0 + k0], &LAh[l0]);
    dma16(&Ah[a1 + k0], &LAh[l1]);
    dma16(&Bh[b0o + k0], &LBh[l0]);
    dma16(&Bh[b1o + k0], &LBh[l1]);
    if constexpr (NSPLIT > 1) {
      dma16(&Al[a0 + k0], &LAl[l0]);
      dma16(&Al[a1 + k0], &LAl[l1]);
      dma16(&Bl[b0o + k0], &LBl[l0]);
      dma16(&Bl[b1o + k0], &LBl[l1]);
    }
    __syncthreads();

    short8 fah[4], fbh[4], fal[4], fbl[4];
#pragma unroll
    for (int i = 0; i < 4; ++i) {
      int ar = (wm + i * 16 + l16) * 32 + quad * 8;
      int br = (wn + i * 16 + l16) * 32 + quad * 8;
      fah[i] = *(const short8*)&LAh[ar];
      fbh[i] = *(const short8*)&LBh[br];
      if constexpr (NSPLIT > 1) {
        fal[i] = *(const short8*)&LAl[ar];
        fbl[i] = *(const short8*)&LBl[br];
      }
    }
#pragma unroll
    for (int i = 0; i < 4; ++i)
#pragma unroll
      for (int j = 0; j < 4; ++j) {
        acc[i][j] = __builtin_amdgcn_mfma_f32_16x16x32_bf16(fah[i], fbh[j], acc[i][j], 0, 0, 0);
        if constexpr (NSPLIT > 1) {
          acc[i][j] = __builtin_amdgcn_mfma_f32_16x16x32_bf16(fah[i], fbl[j], acc[i][j], 0, 0, 0);
          acc[i][j] = __builtin_amdgcn_mfma_f32_16x16x32_bf16(fal[i], fbh[j], acc[i][j], 0, 0, 0);
        }
      }
    __syncthreads();
  }

  // epilogue: C/D layout col(n)=lane&15, row(m)=quad*4+reg  [m89-verified]
#pragma unroll
  for (int j = 0; j < 4; ++j) {
    int n = bn + wn + j * 16 + l16;
    float bv = 0.f;
    float* cp = (float*)Cv;
    int stride = N, ncol = n;
    bool dotanh = false;
    if (MODE == 3) {
      if (n < A_OFF) { bv = bias[n]; stride = A_OFF; dotanh = true; }
      else { bv = bias2[n - A_OFF]; cp = (float*)Cv2; stride = A_ATTN; ncol = n - A_OFF; }
    } else if (MODE == 0) {
      if (bias) bv = bias[n];
    }
#pragma unroll
    for (int i = 0; i < 4; ++i) {
      int mbase = bm + wm + i * 16 + quad * 4;
#pragma unroll
      for (int reg = 0; reg < 4; ++reg) {
        int m = mbase + reg;
        if (m >= M) continue;
        float c = acc[i][j][reg] + bv;
        if (MODE == 3 && dotanh) { float t = __expf(2.f * c); c = 1.f - 2.f / (t + 1.f); }
        if (MODE == 2) {
          int vv = m / SLENs;
          int s = m - vv * SLENs;
          int hh2 = n >> 5, dd = n & 31;
          ((unsigned short*)Cv)[((size_t)(vv * 8 + hh2) * SLENs + s) * 32 + dd] = f2bf(c);
        } else {
          cp[(size_t)m * stride + ncol] = c;
        }
      }
    }
  }
}

// ---------------------------------------------------------------------------
// Fused softmax + per-sample record build. Wave = one (q,h) row (384 samples,
// 6 per lane, j = v*64 + lane). Decode: v=j>>6, l=(lane>>4)&3, p=(lane>>2)&3,
// z=lane&3 — identical to the old per-sample decode (h*384 offsets vanish
// mod the field widths). Records (SoA, 12B/sample):
//   rbase = (start + y0*Wl + x0) << 6 | fx | fy<<1
//   rw    = { bf(w01)<<16 | bf(w00),  bf(w11)<<16 | bf(w10) }
// ---------------------------------------------------------------------------
__global__ __launch_bounds__(256) void softpre_kernel(
    const float* __restrict__ ref, const float* __restrict__ offs,
    const float* __restrict__ attn, int* __restrict__ rbase,
    uint2* __restrict__ rw) {
  const int lane = threadIdx.x & 63;
  const int row = blockIdx.x * 4 + (threadIdx.x >> 6);   // q*8 + h
  const int q = row >> 3;

  const float* ap = attn + (size_t)row * 384;
  float vals[6];
  float mx = -1e30f;
#pragma unroll
  for (int i = 0; i < 6; ++i) { vals[i] = ap[lane + i * 64]; mx = fmaxf(mx, vals[i]); }
#pragma unroll
  for (int o = 32; o > 0; o >>= 1) mx = fmaxf(mx, __shfl_xor(mx, o, 64));
  float s = 0.f;
#pragma unroll
  for (int i = 0; i < 6; ++i) { vals[i] = __expf(vals[i] - mx); s += vals[i]; }
#pragma unroll
  for (int o = 32; o > 0; o >>= 1) s += __shfl_xor(s, o, 64);
  const float inv = 1.0f / s;

  const int l = (lane >> 4) & 3;
  const int z = lane & 3;
  const int Wl = 64 >> l;
  const int start = (l == 0) ? 0 : (l == 1 ? 4096 : (l == 2 ? 5120 : 5376));
  const float sc = 0.5f * (float)(Wl - 1);
  const float2* op = (const float2*)offs + (size_t)row * 384;
  const float* rq = ref + (size_t)q * (NVv * 4 * 4 * 2);

  for (int v = 0; v < 6; ++v) {
    int j = v * 64 + lane;
    float w = vals[v] * inv;
    float2 o = op[j];
    const float* rp = rq + ((v * 4 + l) * 4 + z) * 2;
    float rx = rp[0], ry = rp[1];
    float x = fminf(1.f, fmaxf(-1.f, rx + o.x));
    float y = fminf(1.f, fmaxf(-1.f, ry + o.y));
    float xp = (x + 1.f) * sc, yp = (y + 1.f) * sc;
    float x0f = floorf(xp), y0f = floorf(yp);
    int x0 = (int)x0f, y0 = (int)y0f;      // xp,yp >= 0 -> trunc == floor
    float wx = xp - x0f, wy = yp - y0f;
    int fx = (x0 + 1 < Wl) ? 1 : 0;
    int fy = (y0 + 1 < Wl) ? 2 : 0;
    float wxw = wx * w, wmx = w - wxw;
    float w01 = wxw * (1.f - wy), w11 = wxw * wy;
    float w00 = wmx * (1.f - wy), w10 = wmx * wy;
    int idx = row * 384 + j;
    rbase[idx] = ((start + y0 * Wl + x0) << 6) | fx | fy;
    rw[idx] = make_uint2(((unsigned)f2bf(w01) << 16) | f2bf(w00),
                         ((unsigned)f2bf(w11) << 16) | f2bf(w10));
  }
}

// ---------------------------------------------------------------------------
// Sampling v3c (UNCHANGED from round 7 — verified): wave = one (q,h).
// lane bits: [1:0]=e (channel oct), [2]=cx, [3]=cy, [5:4]=r.
// v/l loops at unroll 1 (round-5 spill lesson); lane r's records spaced 4
// apart (round-6 indexing lesson).
// ---------------------------------------------------------------------------
__global__ __launch_bounds__(256) void sample_kernel(
    const int* __restrict__ rbase, const uint2* __restrict__ rw,
    const unsigned short* __restrict__ val_t,
    unsigned short* __restrict__ oph, unsigned short* __restrict__ opl) {
  const int h  = blockIdx.x & 7;
  const int qt = blockIdx.x >> 3;
  const int lane = threadIdx.x & 63;
  const int q  = qt * 4 + (threadIdx.x >> 6);

  const int e16 = (lane & 3) << 4;
  const int cxm = ((lane >> 2) & 1) << 6;   // 0 or 64
  const bool cy = (lane >> 3) & 1;
  const int r   = lane >> 4;

  const int rb0 = q * A_ATTN + h * 384 + r;
  const int*  rb  = rbase + rb0;
  const uint2* rwp = rw + rb0;

  float acc[8] = {};
  int ib = 0;

#pragma unroll 1
  for (int v = 0; v < 6; ++v) {
    const char* sb = (const char*)val_t + (size_t)(v * 8 + h) * (SLENs * 64);
#pragma unroll 1
    for (int l = 0; l < 4; ++l) {
      const int cym = cy ? (2 << (11 - l)) : 0;
#pragma unroll
      for (int i = 0; i < 4; ++i) {
        int ri = ib + i * 4;            // lane r's records: r + ib + 4i
        int bf = rb[ri];
        uint2 pk2 = rwp[ri];
        int voff = ((bf & -64) | e16) + ((bf << 6) & cxm) + ((bf << (11 - l)) & cym);
        uint4 u = *(const uint4*)(sb + voff);
        unsigned int pk = cy ? pk2.y : pk2.x;
        float wl_ = __uint_as_float(cxm ? (pk & 0xFFFF0000u) : (pk << 16));
        acc[0] = fmaf(wl_, __uint_as_float(u.x << 16),          acc[0]);
        acc[1] = fmaf(wl_, __uint_as_float(u.x & 0xFFFF0000u),  acc[1]);
        acc[2] = fmaf(wl_, __uint_as_float(u.y << 16),          acc[2]);
        acc[3] = fmaf(wl_, __uint_as_float(u.y & 0xFFFF0000u),  acc[3]);
        acc[4] = fmaf(wl_, __uint_as_float(u.z << 16),          acc[4]);
        acc[5] = fmaf(wl_, __uint_as_float(u.z & 0xFFFF0000u),  acc[5]);
        acc[6] = fmaf(wl_, __uint_as_float(u.w << 16),          acc[6]);
        acc[7] = fmaf(wl_, __uint_as_float(u.w & 0xFFFF0000u),  acc[7]);
      }
      ib += 16;
    }
  }

#pragma unroll
  for (int m = 4; m <= 32; m <<= 1)
#pragma unroll
    for (int j = 0; j < 8; ++j) acc[j] += __shfl_xor(acc[j], m, 64);

  if (lane < 4) {
    int off = q * EMB + h * 32 + lane * 8;
    ushort4 h0, h1, lo0, lo1;
    h0.x = f2bf(acc[0]); h0.y = f2bf(acc[1]); h0.z = f2bf(acc[2]); h0.w = f2bf(acc[3]);
    h1.x = f2bf(acc[4]); h1.y = f2bf(acc[5]); h1.z = f2bf(acc[6]); h1.w = f2bf(acc[7]);
    lo0.x = f2bf(acc[0] - bf2f(h0.x)); lo0.y = f2bf(acc[1] - bf2f(h0.y));
    lo0.z = f2bf(acc[2] - bf2f(h0.z)); lo0.w = f2bf(acc[3] - bf2f(h0.w));
    lo1.x = f2bf(acc[4] - bf2f(h1.x)); lo1.y = f2bf(acc[5] - bf2f(h1.y));
    lo1.z = f2bf(acc[6] - bf2f(h1.z)); lo1.w = f2bf(acc[7] - bf2f(h1.w));
    *(ushort4*)&oph[off] = h0;  *(ushort4*)&oph[off + 4] = h1;
    *(ushort4*)&opl[off] = lo0; *(ushort4*)&opl[off + 4] = lo1;
  }
}

// ---------------------------------------------------------------------------
extern "C" void kernel_launch(void* const* d_in, const int* in_sizes, int n_in,
                              void* d_out, int out_size, void* d_ws, size_t ws_size,
                              hipStream_t stream) {
  const float* queries    = (const float*)d_in[0];
  const float* ref_points = (const float*)d_in[1];
  const float* value      = (const float*)d_in[2];
  const float* Wv    = (const float*)d_in[4];
  const float* Woff  = (const float*)d_in[5];
  const float* boff  = (const float*)d_in[6];
  const float* Wattn = (const float*)d_in[7];
  const float* battn = (const float*)d_in[8];
  const float* Wout  = (const float*)d_in[9];
  float* out = (float*)d_out;

  // ws layout, byte offsets (peak 155.06 MB, proven fit). Wqh/Wql (the
  // contiguous Woff||Wattn splits) overlay rbase/rw — dead before softpre.
  char* W = (char*)d_ws;
  float* offs            = (float*)(W + 0);                  // 39,321,600
  float* attn            = (float*)(W + 39321600);           // 19,660,800
  unsigned short* val_t  = (unsigned short*)(W + 58982400);  // 16,711,680
  unsigned short* qh     = (unsigned short*)(W + 75694080);  //    819,200
  unsigned short* ql     = (unsigned short*)(W + 76513280);  //    819,200
  unsigned short* vh     = (unsigned short*)(W + 77332480);  // 16,711,680
  unsigned short* Wvh    = (unsigned short*)(W + 94044160);  //    131,072
  unsigned short* Wouth  = (unsigned short*)(W + 94175232);  //    131,072
  unsigned short* Woutl  = (unsigned short*)(W + 94306304);  //    131,072
  unsigned short* oph    = (unsigned short*)(W + 94437376);  //    819,200
  unsigned short* opl    = (unsigned short*)(W + 95256576);  //    819,200
  int*   rbase           = (int*)(W + 96075776);             // 19,660,800
  uint2* rw              = (uint2*)(W + 115736576);          // 39,321,600
  unsigned short* Wqh    = (unsigned short*)(W + 96075776);  // overlay 4,718,592
  unsigned short* Wql    = (unsigned short*)(W + 100794368); // overlay 4,718,592

  dim3 blk(256);

  // 1. split all GEMM operands to bf16 hi(/lo); Woff/Wattn land contiguous
  split_all_kernel<<<10992, blk, 0, stream>>>(
      queries, value, Woff, Wattn, Wv, Wout,
      qh, ql, vh, Wqh, Wql, Wqh + 1572864, Wql + 1572864, Wvh, Wouth, Woutl);
  // 2. fused offs/attn GEMM: N = 6144 + 3072 = 9216
  gemmb_kernel<3, 3><<<dim3(9216 / 128, (QQ + 127) / 128), blk, 0, stream>>>(
      qh, ql, Wqh, Wql, boff, battn, offs, attn, QQ, 9216, EMB);
  // 3. val_t (bf16, [v][h][s][d]) = (value @ Wv.T) permuted — hi-only
  gemmb_kernel<1, 2><<<dim3(EMB / 128, (NVv * SLENs) / 128), blk, 0, stream>>>(
      vh, nullptr, Wvh, nullptr, nullptr, nullptr, val_t, nullptr,
      NVv * SLENs, EMB, EMB);
  // 4. fused softmax + record build (overwrites Wqh/Wql — dead)
  softpre_kernel<<<(QQ * NHh) / 4, blk, 0, stream>>>(
      ref_points, offs, attn, rbase, rw);
  // 5. bilinear sampling + weighted accumulation -> out_pre bf16 hi/lo
  sample_kernel<<<QQ * NHh / 4, blk, 0, stream>>>(rbase, rw, val_t, oph, opl);
  // 6. out = out_pre @ Wout.T
  gemmb_kernel<3, 0><<<dim3(EMB / 128, (QQ + 127) / 128), blk, 0, stream>>>(
      oph, opl, Wouth, Woutl, nullptr, nullptr, out, nullptr, QQ, EMB, EMB);
}

// Round 9
// 252.027 us; speedup vs baseline: 5.5060x; 1.1674x over previous
//
#include <hip/hip_runtime.h>
#include <hip/hip_bf16.h>
#include <math.h>

#define NHh   8
#define EMB   256
#define HDd   32
#define NVv   6
#define SLENs 5440
#define QQ    1600
#define A_ATTN 3072   // NH*NV*NL*NP*NZ
#define A_OFF  6144
#define SAMP_TOT (QQ * A_ATTN)   // 4,915,200

typedef __attribute__((ext_vector_type(8))) short short8;
typedef __attribute__((ext_vector_type(4))) float f32x4;

__device__ __forceinline__ unsigned short f2bf(float f) {
  __hip_bfloat16 h = __float2bfloat16(f);
  return *(unsigned short*)&h;
}
__device__ __forceinline__ float bf2f(unsigned short u) {
  return __uint_as_float((unsigned int)u << 16);
}

// async global->LDS DMA, 16B per lane. LDS dest semantics: wave-uniform base
// + lane*16 (m104/m108) — caller must pass lane-ordered contiguous LDS addrs.
__device__ __forceinline__ void dma16(const unsigned short* g, unsigned short* l) {
  __builtin_amdgcn_global_load_lds(
      (const __attribute__((address_space(1))) unsigned int*)g,
      (__attribute__((address_space(3))) unsigned int*)l, 16, 0, 0);
}

// ---------------------------------------------------------------------------
// One-shot fp32 -> bf16 hi(/lo) split of all GEMM operands.
// ---------------------------------------------------------------------------
__global__ __launch_bounds__(256) void split_all_kernel(
    const float* __restrict__ q, const float* __restrict__ value,
    const float* __restrict__ Woff, const float* __restrict__ Wattn,
    const float* __restrict__ Wv, const float* __restrict__ Wout,
    unsigned short* __restrict__ qh, unsigned short* __restrict__ ql,
    unsigned short* __restrict__ vh,
    unsigned short* __restrict__ Woffh, unsigned short* __restrict__ Woffl,
    unsigned short* __restrict__ Wattnh, unsigned short* __restrict__ Wattnl,
    unsigned short* __restrict__ Wvh,
    unsigned short* __restrict__ Wouth, unsigned short* __restrict__ Woutl) {
  int i4 = blockIdx.x * 256 + threadIdx.x;   // < 2,813,952
  const float* src; unsigned short* dh; unsigned short* dl; int loc;
  if      (i4 < 102400)  { src = q;     dh = qh;     dl = ql;     loc = i4; }
  else if (i4 < 2191360) { src = value; dh = vh;     dl = nullptr; loc = i4 - 102400; }
  else if (i4 < 2584576) { src = Woff;  dh = Woffh;  dl = Woffl;  loc = i4 - 2191360; }
  else if (i4 < 2781184) { src = Wattn; dh = Wattnh; dl = Wattnl; loc = i4 - 2584576; }
  else if (i4 < 2797568) { src = Wv;    dh = Wvh;    dl = nullptr; loc = i4 - 2781184; }
  else                   { src = Wout;  dh = Wouth;  dl = Woutl;  loc = i4 - 2797568; }
  float4 x = ((const float4*)src)[loc];
  ushort4 hh;
  hh.x = f2bf(x.x); hh.y = f2bf(x.y); hh.z = f2bf(x.z); hh.w = f2bf(x.w);
  ((ushort4*)dh)[loc] = hh;
  if (dl) {
    ushort4 ll;
    ll.x = f2bf(x.x - bf2f(hh.x)); ll.y = f2bf(x.y - bf2f(hh.y));
    ll.z = f2bf(x.z - bf2f(hh.z)); ll.w = f2bf(x.w - bf2f(hh.w));
    ((ushort4*)dl)[loc] = ll;
  }
}

// ---------------------------------------------------------------------------
// bf16 MFMA GEMM on pre-split operands, global_load_lds staging.
// NSPLIT=3: hh+hl+lh; NSPLIT=1: hh. Tile 128x128, BK=32, 4 waves 2x2.
// MODE 0: f32 store to Cv (+bias if non-null)
// MODE 2: bf16 permuted store (val): m=(v*SLEN+s), n=(h*32+d)
// MODE 3: fused offs/attn: n<A_OFF -> tanh(c+bias[n]) into Cv (stride A_OFF);
//         else c+bias2[n-A_OFF] into Cv2 (stride A_ATTN). 128-tiles never
//         straddle n=6144 so the branch is block-uniform.
// ---------------------------------------------------------------------------
template <int NSPLIT, int MODE>
__global__ __launch_bounds__(256) void gemmb_kernel(
    const unsigned short* __restrict__ Ah, const unsigned short* __restrict__ Al,
    const unsigned short* __restrict__ Bh, const unsigned short* __restrict__ Bl,
    const float* __restrict__ bias, const float* __restrict__ bias2,
    void* __restrict__ Cv, void* __restrict__ Cv2,
    int M, int N, int K) {
  __shared__ unsigned short LAh[128 * 32], LBh[128 * 32];
  __shared__ unsigned short LAl[NSPLIT > 1 ? 128 * 32 : 8];
  __shared__ unsigned short LBl[NSPLIT > 1 ? 128 * 32 : 8];

  const int tid = threadIdx.x;
  const int bm = blockIdx.y * 128, bn = blockIdx.x * 128;
  const int lane = tid & 63, w = tid >> 6;
  const int wm = (w & 1) * 64, wn = (w >> 1) * 64;
  const int l16 = lane & 15, quad = lane >> 4;

  const int c0 = tid, c1 = tid + 256;
  const int r0 = c0 >> 2, s0 = (c0 & 3) * 8;
  const int r1 = c1 >> 2, s1 = (c1 & 3) * 8;
  const size_t a0 = (size_t)min(bm + r0, M - 1) * K + s0;
  const size_t a1 = (size_t)min(bm + r1, M - 1) * K + s1;
  const size_t b0o = (size_t)(bn + r0) * K + s0;
  const size_t b1o = (size_t)(bn + r1) * K + s1;
  const int l0 = c0 * 8, l1 = c1 * 8;

  f32x4 acc[4][4] = {};

  for (int k0 = 0; k0 < K; k0 += 32) {
    dma16(&Ah[a0 + k0], &LAh[l0]);
    dma16(&Ah[a1 + k0], &LAh[l1]);
    dma16(&Bh[b0o + k0], &LBh[l0]);
    dma16(&Bh[b1o + k0], &LBh[l1]);
    if constexpr (NSPLIT > 1) {
      dma16(&Al[a0 + k0], &LAl[l0]);
      dma16(&Al[a1 + k0], &LAl[l1]);
      dma16(&Bl[b0o + k0], &LBl[l0]);
      dma16(&Bl[b1o + k0], &LBl[l1]);
    }
    __syncthreads();

    short8 fah[4], fbh[4], fal[4], fbl[4];
#pragma unroll
    for (int i = 0; i < 4; ++i) {
      int ar = (wm + i * 16 + l16) * 32 + quad * 8;
      int br = (wn + i * 16 + l16) * 32 + quad * 8;
      fah[i] = *(const short8*)&LAh[ar];
      fbh[i] = *(const short8*)&LBh[br];
      if constexpr (NSPLIT > 1) {
        fal[i] = *(const short8*)&LAl[ar];
        fbl[i] = *(const short8*)&LBl[br];
      }
    }
#pragma unroll
    for (int i = 0; i < 4; ++i)
#pragma unroll
      for (int j = 0; j < 4; ++j) {
        acc[i][j] = __builtin_amdgcn_mfma_f32_16x16x32_bf16(fah[i], fbh[j], acc[i][j], 0, 0, 0);
        if constexpr (NSPLIT > 1) {
          acc[i][j] = __builtin_amdgcn_mfma_f32_16x16x32_bf16(fah[i], fbl[j], acc[i][j], 0, 0, 0);
          acc[i][j] = __builtin_amdgcn_mfma_f32_16x16x32_bf16(fal[i], fbh[j], acc[i][j], 0, 0, 0);
        }
      }
    __syncthreads();
  }

  // epilogue: C/D layout col(n)=lane&15, row(m)=quad*4+reg  [m89-verified]
#pragma unroll
  for (int j = 0; j < 4; ++j) {
    int n = bn + wn + j * 16 + l16;
    float bv = 0.f;
    float* cp = (float*)Cv;
    int stride = N, ncol = n;
    bool dotanh = false;
    if (MODE == 3) {
      if (n < A_OFF) { bv = bias[n]; stride = A_OFF; dotanh = true; }
      else { bv = bias2[n - A_OFF]; cp = (float*)Cv2; stride = A_ATTN; ncol = n - A_OFF; }
    } else if (MODE == 0) {
      if (bias) bv = bias[n];
    }
#pragma unroll
    for (int i = 0; i < 4; ++i) {
      int mbase = bm + wm + i * 16 + quad * 4;
#pragma unroll
      for (int reg = 0; reg < 4; ++reg) {
        int m = mbase + reg;
        if (m >= M) continue;
        float c = acc[i][j][reg] + bv;
        if (MODE == 3 && dotanh) { float t = __expf(2.f * c); c = 1.f - 2.f / (t + 1.f); }
        if (MODE == 2) {
          int vv = m / SLENs;
          int s = m - vv * SLENs;
          int hh2 = n >> 5, dd = n & 31;
          ((unsigned short*)Cv)[((size_t)(vv * 8 + hh2) * SLENs + s) * 32 + dd] = f2bf(c);
        } else {
          cp[(size_t)m * stride + ncol] = c;
        }
      }
    }
  }
}

// ---------------------------------------------------------------------------
// Fused softmax + record build + sampling. Wave = one (q,h).
// Phase 1 (softpre, verified round 8): softmax over 384 (6/lane, j=v*64+lane;
// decode l=(lane>>4)&3, z=lane&3), builds 384 records into a WAVE-PRIVATE
// LDS slice (no barrier needed — single wave is both producer and consumer):
//   Lrb = (start + y0*Wl + x0) << 6 | fx | fy<<1
//   Lrw = { bf(w01)<<16 | bf(w00),  bf(w11)<<16 | bf(w10) }
// Phase 2 (v3c sampling, verified round 7): lane bits [1:0]=e (channel oct),
// [2]=cx, [3]=cy, [5:4]=r. v/l loops at unroll 1 (round-5 spill lesson);
// lane r's records spaced 4 apart (round-6 indexing lesson). Record reads
// are 16-lane same-address ds_reads -> broadcast, conflict-free.
// ---------------------------------------------------------------------------
__global__ __launch_bounds__(256) void sample_kernel(
    const float* __restrict__ ref, const float* __restrict__ offs,
    const float* __restrict__ attn, const unsigned short* __restrict__ val_t,
    unsigned short* __restrict__ oph, unsigned short* __restrict__ opl) {
  __shared__ int   Lrb[4][384];
  __shared__ uint2 Lrw[4][384];

  const int h   = blockIdx.x & 7;      // XCD L2 affinity: 6 slices ~2.1MB
  const int qt  = blockIdx.x >> 3;
  const int wid = threadIdx.x >> 6;
  const int lane = threadIdx.x & 63;
  const int q   = qt * 4 + wid;
  const int row = q * 8 + h;

  // ---- phase 1: softmax + records ----
  {
    const float* ap = attn + (size_t)row * 384;
    float vals[6];
    float mx = -1e30f;
#pragma unroll
    for (int i = 0; i < 6; ++i) { vals[i] = ap[lane + i * 64]; mx = fmaxf(mx, vals[i]); }
#pragma unroll
    for (int o = 32; o > 0; o >>= 1) mx = fmaxf(mx, __shfl_xor(mx, o, 64));
    float s = 0.f;
#pragma unroll
    for (int i = 0; i < 6; ++i) { vals[i] = __expf(vals[i] - mx); s += vals[i]; }
#pragma unroll
    for (int o = 32; o > 0; o >>= 1) s += __shfl_xor(s, o, 64);
    const float inv = 1.0f / s;

    const int l = (lane >> 4) & 3;
    const int z = lane & 3;
    const int Wl = 64 >> l;
    const int start = (l == 0) ? 0 : (l == 1 ? 4096 : (l == 2 ? 5120 : 5376));
    const float sc = 0.5f * (float)(Wl - 1);
    const float2* op = (const float2*)offs + (size_t)row * 384;
    const float* rq = ref + (size_t)q * (NVv * 4 * 4 * 2);

#pragma unroll 1
    for (int v = 0; v < 6; ++v) {
      int j = v * 64 + lane;
      float w = vals[v] * inv;
      float2 o = op[j];
      const float* rp = rq + ((v * 4 + l) * 4 + z) * 2;
      float rx = rp[0], ry = rp[1];
      float x = fminf(1.f, fmaxf(-1.f, rx + o.x));
      float y = fminf(1.f, fmaxf(-1.f, ry + o.y));
      float xp = (x + 1.f) * sc, yp = (y + 1.f) * sc;
      float x0f = floorf(xp), y0f = floorf(yp);
      int x0 = (int)x0f, y0 = (int)y0f;      // xp,yp >= 0 -> trunc == floor
      float wx = xp - x0f, wy = yp - y0f;
      int fx = (x0 + 1 < Wl) ? 1 : 0;
      int fy = (y0 + 1 < Wl) ? 2 : 0;
      float wxw = wx * w, wmx = w - wxw;
      float w01 = wxw * (1.f - wy), w11 = wxw * wy;
      float w00 = wmx * (1.f - wy), w10 = wmx * wy;
      Lrb[wid][j] = ((start + y0 * Wl + x0) << 6) | fx | fy;
      Lrw[wid][j] = make_uint2(((unsigned)f2bf(w01) << 16) | f2bf(w00),
                               ((unsigned)f2bf(w11) << 16) | f2bf(w10));
    }
  }
  // no __syncthreads: each wave consumes only its own Lrb/Lrw slice

  // ---- phase 2: sampling ----
  const int e16 = (lane & 3) << 4;
  const int cxm = ((lane >> 2) & 1) << 6;   // 0 or 64
  const bool cy = (lane >> 3) & 1;
  const int r   = lane >> 4;

  float acc[8] = {};
  int ib = r;

#pragma unroll 1
  for (int v = 0; v < 6; ++v) {
    const char* sb = (const char*)val_t + (size_t)(v * 8 + h) * (SLENs * 64);
#pragma unroll 1
    for (int l = 0; l < 4; ++l) {
      const int cym = cy ? (2 << (11 - l)) : 0;
#pragma unroll
      for (int i = 0; i < 4; ++i) {
        int ri = ib + i * 4;            // lane r's records: r + ib + 4i
        int bf = Lrb[wid][ri];
        uint2 pk2 = Lrw[wid][ri];
        int voff = ((bf & -64) | e16) + ((bf << 6) & cxm) + ((bf << (11 - l)) & cym);
        uint4 u = *(const uint4*)(sb + voff);
        unsigned int pk = cy ? pk2.y : pk2.x;
        float wl_ = __uint_as_float(cxm ? (pk & 0xFFFF0000u) : (pk << 16));
        acc[0] = fmaf(wl_, __uint_as_float(u.x << 16),          acc[0]);
        acc[1] = fmaf(wl_, __uint_as_float(u.x & 0xFFFF0000u),  acc[1]);
        acc[2] = fmaf(wl_, __uint_as_float(u.y << 16),          acc[2]);
        acc[3] = fmaf(wl_, __uint_as_float(u.y & 0xFFFF0000u),  acc[3]);
        acc[4] = fmaf(wl_, __uint_as_float(u.z << 16),          acc[4]);
        acc[5] = fmaf(wl_, __uint_as_float(u.z & 0xFFFF0000u),  acc[5]);
        acc[6] = fmaf(wl_, __uint_as_float(u.w << 16),          acc[6]);
        acc[7] = fmaf(wl_, __uint_as_float(u.w & 0xFFFF0000u),  acc[7]);
      }
      ib += 16;
    }
  }

#pragma unroll
  for (int m = 4; m <= 32; m <<= 1)
#pragma unroll
    for (int j = 0; j < 8; ++j) acc[j] += __shfl_xor(acc[j], m, 64);

  if (lane < 4) {
    int off = q * EMB + h * 32 + lane * 8;
    ushort4 h0, h1, lo0, lo1;
    h0.x = f2bf(acc[0]); h0.y = f2bf(acc[1]); h0.z = f2bf(acc[2]); h0.w = f2bf(acc[3]);
    h1.x = f2bf(acc[4]); h1.y = f2bf(acc[5]); h1.z = f2bf(acc[6]); h1.w = f2bf(acc[7]);
    lo0.x = f2bf(acc[0] - bf2f(h0.x)); lo0.y = f2bf(acc[1] - bf2f(h0.y));
    lo0.z = f2bf(acc[2] - bf2f(h0.z)); lo0.w = f2bf(acc[3] - bf2f(h0.w));
    lo1.x = f2bf(acc[4] - bf2f(h1.x)); lo1.y = f2bf(acc[5] - bf2f(h1.y));
    lo1.z = f2bf(acc[6] - bf2f(h1.z)); lo1.w = f2bf(acc[7] - bf2f(h1.w));
    *(ushort4*)&oph[off] = h0;  *(ushort4*)&oph[off + 4] = h1;
    *(ushort4*)&opl[off] = lo0; *(ushort4*)&opl[off + 4] = lo1;
  }
}

// ---------------------------------------------------------------------------
extern "C" void kernel_launch(void* const* d_in, const int* in_sizes, int n_in,
                              void* d_out, int out_size, void* d_ws, size_t ws_size,
                              hipStream_t stream) {
  const float* queries    = (const float*)d_in[0];
  const float* ref_points = (const float*)d_in[1];
  const float* value      = (const float*)d_in[2];
  const float* Wv    = (const float*)d_in[4];
  const float* Woff  = (const float*)d_in[5];
  const float* boff  = (const float*)d_in[6];
  const float* Wattn = (const float*)d_in[7];
  const float* battn = (const float*)d_in[8];
  const float* Wout  = (const float*)d_in[9];
  float* out = (float*)d_out;

  // ws layout, byte offsets (well under the proven 155 MB peak; rbase/rw
  // arrays are gone — records now live in sample_kernel's LDS).
  char* W = (char*)d_ws;
  float* offs            = (float*)(W + 0);                  // 39,321,600
  float* attn            = (float*)(W + 39321600);           // 19,660,800
  unsigned short* val_t  = (unsigned short*)(W + 58982400);  // 16,711,680
  unsigned short* qh     = (unsigned short*)(W + 75694080);  //    819,200
  unsigned short* ql     = (unsigned short*)(W + 76513280);  //    819,200
  unsigned short* vh     = (unsigned short*)(W + 77332480);  // 16,711,680
  unsigned short* Wvh    = (unsigned short*)(W + 94044160);  //    131,072
  unsigned short* Wouth  = (unsigned short*)(W + 94175232);  //    131,072
  unsigned short* Woutl  = (unsigned short*)(W + 94306304);  //    131,072
  unsigned short* oph    = (unsigned short*)(W + 94437376);  //    819,200
  unsigned short* opl    = (unsigned short*)(W + 95256576);  //    819,200
  unsigned short* Wqh    = (unsigned short*)(W + 96075776);  //  4,718,592 (Woff||Wattn hi)
  unsigned short* Wql    = (unsigned short*)(W + 100794368); //  4,718,592 (Woff||Wattn lo)

  dim3 blk(256);

  // 1. split all GEMM operands to bf16 hi(/lo); Woff/Wattn land contiguous
  split_all_kernel<<<10992, blk, 0, stream>>>(
      queries, value, Woff, Wattn, Wv, Wout,
      qh, ql, vh, Wqh, Wql, Wqh + 1572864, Wql + 1572864, Wvh, Wouth, Woutl);
  // 2. fused offs/attn GEMM: N = 6144 + 3072 = 9216
  gemmb_kernel<3, 3><<<dim3(9216 / 128, (QQ + 127) / 128), blk, 0, stream>>>(
      qh, ql, Wqh, Wql, boff, battn, offs, attn, QQ, 9216, EMB);
  // 3. val_t (bf16, [v][h][s][d]) = (value @ Wv.T) permuted — hi-only
  gemmb_kernel<1, 2><<<dim3(EMB / 128, (NVv * SLENs) / 128), blk, 0, stream>>>(
      vh, nullptr, Wvh, nullptr, nullptr, nullptr, val_t, nullptr,
      NVv * SLENs, EMB, EMB);
  // 4. fused softmax + record build + sampling -> out_pre bf16 hi/lo
  sample_kernel<<<QQ * NHh / 4, blk, 0, stream>>>(
      ref_points, offs, attn, val_t, oph, opl);
  // 5. out = out_pre @ Wout.T
  gemmb_kernel<3, 0><<<dim3(EMB / 128, (QQ + 127) / 128), blk, 0, stream>>>(
      oph, opl, Wouth, Woutl, nullptr, nullptr, out, nullptr, QQ, EMB, EMB);
}

// Round 10
// 238.468 us; speedup vs baseline: 5.8191x; 1.0569x over previous
//
#include <hip/hip_runtime.h>
#include <hip/hip_bf16.h>
#include <math.h>

#define NHh   8
#define EMB   256
#define HDd   32
#define NVv   6
#define SLENs 5440
#define QQ    1600
#define A_ATTN 3072   // NH*NV*NL*NP*NZ
#define A_OFF  6144

typedef _Float16 half8 __attribute__((ext_vector_type(8)));
typedef __attribute__((ext_vector_type(4))) float f32x4;

__device__ __forceinline__ unsigned short f2bf(float f) {
  __hip_bfloat16 h = __float2bfloat16(f);
  return *(unsigned short*)&h;
}
__device__ __forceinline__ unsigned short f2h(float f) {
  _Float16 h = (_Float16)f;
  return __builtin_bit_cast(unsigned short, h);
}
__device__ __forceinline__ float h2f(unsigned short u) {
  return (float)__builtin_bit_cast(_Float16, u);
}

// async global->LDS DMA, 16B per lane. LDS dest semantics: wave-uniform base
// + lane*16 (m104/m108) — caller must pass lane-ordered contiguous LDS addrs.
__device__ __forceinline__ void dma16(const unsigned short* g, unsigned short* l) {
  __builtin_amdgcn_global_load_lds(
      (const __attribute__((address_space(1))) unsigned int*)g,
      (__attribute__((address_space(3))) unsigned int*)l, 16, 0, 0);
}

// ---------------------------------------------------------------------------
// One-shot fp32 -> fp16 conversion of all GEMM operands (single, no hi/lo:
// fp16's 2^-11 rel err replaces the bf16 3-split — round-9 analysis).
// Woff/Wattn land contiguous in Wq16 (Wattn at element 1,572,864).
// ---------------------------------------------------------------------------
__global__ __launch_bounds__(256) void split_h_kernel(
    const float* __restrict__ q, const float* __restrict__ value,
    const float* __restrict__ Woff, const float* __restrict__ Wattn,
    const float* __restrict__ Wv, const float* __restrict__ Wout,
    unsigned short* __restrict__ q16, unsigned short* __restrict__ v16,
    unsigned short* __restrict__ Wq16, unsigned short* __restrict__ Wv16,
    unsigned short* __restrict__ Wout16) {
  int i4 = blockIdx.x * 256 + threadIdx.x;   // < 2,813,952 float4-chunks
  const float* src; unsigned short* dst; int loc;
  if      (i4 < 102400)  { src = q;     dst = q16;    loc = i4; }
  else if (i4 < 2191360) { src = value; dst = v16;    loc = i4 - 102400; }
  else if (i4 < 2584576) { src = Woff;  dst = Wq16;   loc = i4 - 2191360; }
  else if (i4 < 2781184) { src = Wattn; dst = Wq16;   loc = i4 - 2584576 + 393216; }
  else if (i4 < 2797568) { src = Wv;    dst = Wv16;   loc = i4 - 2781184; }
  else                   { src = Wout;  dst = Wout16; loc = i4 - 2797568; }
  float4 x = ((const float4*)src)[loc - (src == Woff ? 0 : 0)];
  // note: for the Wattn segment, src index must not include the +393216 dest bias
  if (src == Wattn) x = ((const float4*)src)[loc - 393216];
  ushort4 hh;
  hh.x = f2h(x.x); hh.y = f2h(x.y); hh.z = f2h(x.z); hh.w = f2h(x.w);
  ((ushort4*)dst)[loc] = hh;
}

// ---------------------------------------------------------------------------
// fp16 MFMA GEMM (single-pass): C[m,n] = op( A[m,:]·B[n,:] + bias[n] )
// A: MxK fp16 rows, B: NxK fp16 rows. Tile 128x128, BK=32, 4 waves 2x2,
// global_load_lds staging (16 KB LDS -> 8 blocks/CU).
// MODE 0: f32 store to Cv (+bias if non-null)
// MODE 2: bf16 permuted store (val_t): m=(v*SLEN+s), n=(h*32+d)
// MODE 3: fused offs/attn, fp16 stores: n<A_OFF -> tanh(c+bias[n]) into Cv
//         (stride A_OFF); else c+bias2 into Cv2 (stride A_ATTN). 128-tiles
//         never straddle n=6144 so the branch is block-uniform.
// ---------------------------------------------------------------------------
template <int MODE>
__global__ __launch_bounds__(256) void gemmh_kernel(
    const unsigned short* __restrict__ Ah, const unsigned short* __restrict__ Bh,
    const float* __restrict__ bias, const float* __restrict__ bias2,
    void* __restrict__ Cv, void* __restrict__ Cv2,
    int M, int N, int K) {
  __shared__ unsigned short LAh[128 * 32], LBh[128 * 32];

  const int tid = threadIdx.x;
  const int bm = blockIdx.y * 128, bn = blockIdx.x * 128;
  const int lane = tid & 63, w = tid >> 6;
  const int wm = (w & 1) * 64, wn = (w >> 1) * 64;
  const int l16 = lane & 15, quad = lane >> 4;

  // staging: 512 16B chunks per array; chunk c -> row c>>2, kcol (c&3)*8,
  // LDS byte off c*16 (lane-ordered contiguous: dma16 requirement).
  const int c0 = tid, c1 = tid + 256;
  const int r0 = c0 >> 2, s0 = (c0 & 3) * 8;
  const int r1 = c1 >> 2, s1 = (c1 & 3) * 8;
  const size_t a0 = (size_t)min(bm + r0, M - 1) * K + s0;
  const size_t a1 = (size_t)min(bm + r1, M - 1) * K + s1;
  const size_t b0o = (size_t)(bn + r0) * K + s0;
  const size_t b1o = (size_t)(bn + r1) * K + s1;
  const int l0 = c0 * 8, l1 = c1 * 8;

  f32x4 acc[4][4] = {};

  for (int k0 = 0; k0 < K; k0 += 32) {
    dma16(&Ah[a0 + k0], &LAh[l0]);
    dma16(&Ah[a1 + k0], &LAh[l1]);
    dma16(&Bh[b0o + k0], &LBh[l0]);
    dma16(&Bh[b1o + k0], &LBh[l1]);
    __syncthreads();

    half8 fa[4], fb[4];
#pragma unroll
    for (int i = 0; i < 4; ++i) {
      int ar = (wm + i * 16 + l16) * 32 + quad * 8;
      int br = (wn + i * 16 + l16) * 32 + quad * 8;
      fa[i] = *(const half8*)&LAh[ar];
      fb[i] = *(const half8*)&LBh[br];
    }
#pragma unroll
    for (int i = 0; i < 4; ++i)
#pragma unroll
      for (int j = 0; j < 4; ++j)
        acc[i][j] = __builtin_amdgcn_mfma_f32_16x16x32_f16(fa[i], fb[j], acc[i][j], 0, 0, 0);
    __syncthreads();
  }

  // epilogue: C/D layout col(n)=lane&15, row(m)=quad*4+reg  [m89-verified]
#pragma unroll
  for (int j = 0; j < 4; ++j) {
    int n = bn + wn + j * 16 + l16;
    float bv = 0.f;
    bool dotanh = false;
    if (MODE == 3) {
      if (n < A_OFF) { bv = bias[n]; dotanh = true; }
      else bv = bias2[n - A_OFF];
    } else if (MODE == 0) {
      if (bias) bv = bias[n];
    }
#pragma unroll
    for (int i = 0; i < 4; ++i) {
      int mbase = bm + wm + i * 16 + quad * 4;
#pragma unroll
      for (int reg = 0; reg < 4; ++reg) {
        int m = mbase + reg;
        if (m >= M) continue;
        float c = acc[i][j][reg] + bv;
        if (MODE == 3) {
          if (dotanh) {
            float t = __expf(2.f * c);
            c = 1.f - 2.f / (t + 1.f);
            ((unsigned short*)Cv)[(size_t)m * A_OFF + n] = f2h(c);
          } else {
            ((unsigned short*)Cv2)[(size_t)m * A_ATTN + (n - A_OFF)] = f2h(c);
          }
        } else if (MODE == 2) {
          int vv = m / SLENs;
          int s = m - vv * SLENs;
          int hh2 = n >> 5, dd = n & 31;
          ((unsigned short*)Cv)[((size_t)(vv * 8 + hh2) * SLENs + s) * 32 + dd] = f2bf(c);
        } else {
          ((float*)Cv)[(size_t)m * N + n] = c;
        }
      }
    }
  }
}

// ---------------------------------------------------------------------------
// Fused softmax + record build + sampling (structure verified round 9).
// Wave = one (q,h). Phase 1: softmax over 384 (6/lane, j=v*64+lane; decode
// l=(lane>>4)&3, z=lane&3), records into WAVE-PRIVATE LDS (no barrier):
//   Lrb = (start + y0*Wl + x0) << 6 | fx | fy<<1
//   Lrw = { bf(w01)<<16 | bf(w00),  bf(w11)<<16 | bf(w10) }
// offs/attn now fp16 (round-10 change): one u32 = (y<<16|x) offset pair.
// Phase 2 (v3c, verified round 7 — UNTOUCHED, val_t stays bf16): lane bits
// [1:0]=e, [2]=cx, [3]=cy, [5:4]=r; v/l loops unroll 1 (round-5 spill
// lesson); lane r's records spaced 4 apart (round-6 indexing lesson).
// Epilogue writes out_pre as SINGLE fp16 (feeds fp16 final GEMM).
// ---------------------------------------------------------------------------
__global__ __launch_bounds__(256) void sample_kernel(
    const float* __restrict__ ref, const unsigned short* __restrict__ offs16,
    const unsigned short* __restrict__ attn16,
    const unsigned short* __restrict__ val_t,
    unsigned short* __restrict__ op16) {
  __shared__ int   Lrb[4][384];
  __shared__ uint2 Lrw[4][384];

  const int h   = blockIdx.x & 7;      // XCD L2 affinity: 6 slices ~2.1MB
  const int qt  = blockIdx.x >> 3;
  const int wid = threadIdx.x >> 6;
  const int lane = threadIdx.x & 63;
  const int q   = qt * 4 + wid;
  const int row = q * 8 + h;

  // ---- phase 1: softmax + records ----
  {
    const unsigned short* ap = attn16 + (size_t)row * 384;
    float vals[6];
    float mx = -1e30f;
#pragma unroll
    for (int i = 0; i < 6; ++i) { vals[i] = h2f(ap[lane + i * 64]); mx = fmaxf(mx, vals[i]); }
#pragma unroll
    for (int o = 32; o > 0; o >>= 1) mx = fmaxf(mx, __shfl_xor(mx, o, 64));
    float s = 0.f;
#pragma unroll
    for (int i = 0; i < 6; ++i) { vals[i] = __expf(vals[i] - mx); s += vals[i]; }
#pragma unroll
    for (int o = 32; o > 0; o >>= 1) s += __shfl_xor(s, o, 64);
    const float inv = 1.0f / s;

    const int l = (lane >> 4) & 3;
    const int z = lane & 3;
    const int Wl = 64 >> l;
    const int start = (l == 0) ? 0 : (l == 1 ? 4096 : (l == 2 ? 5120 : 5376));
    const float sc = 0.5f * (float)(Wl - 1);
    const unsigned int* op = (const unsigned int*)offs16 + (size_t)row * 384;
    const float* rq = ref + (size_t)q * (NVv * 4 * 4 * 2);

#pragma unroll 1
    for (int v = 0; v < 6; ++v) {
      int j = v * 64 + lane;
      float w = vals[v] * inv;
      unsigned int oxy = op[j];              // fp16 pair: lo=x, hi=y
      float ox = h2f((unsigned short)(oxy & 0xFFFF));
      float oy = h2f((unsigned short)(oxy >> 16));
      const float* rp = rq + ((v * 4 + l) * 4 + z) * 2;
      float rx = rp[0], ry = rp[1];
      float x = fminf(1.f, fmaxf(-1.f, rx + ox));
      float y = fminf(1.f, fmaxf(-1.f, ry + oy));
      float xp = (x + 1.f) * sc, yp = (y + 1.f) * sc;
      float x0f = floorf(xp), y0f = floorf(yp);
      int x0 = (int)x0f, y0 = (int)y0f;      // xp,yp >= 0 -> trunc == floor
      float wx = xp - x0f, wy = yp - y0f;
      int fx = (x0 + 1 < Wl) ? 1 : 0;
      int fy = (y0 + 1 < Wl) ? 2 : 0;
      float wxw = wx * w, wmx = w - wxw;
      float w01 = wxw * (1.f - wy), w11 = wxw * wy;
      float w00 = wmx * (1.f - wy), w10 = wmx * wy;
      Lrb[wid][j] = ((start + y0 * Wl + x0) << 6) | fx | fy;
      Lrw[wid][j] = make_uint2(((unsigned)f2bf(w01) << 16) | f2bf(w00),
                               ((unsigned)f2bf(w11) << 16) | f2bf(w10));
    }
  }
  // no __syncthreads: each wave consumes only its own Lrb/Lrw slice

  // ---- phase 2: sampling (bf16 val_t, unchanged) ----
  const int e16 = (lane & 3) << 4;
  const int cxm = ((lane >> 2) & 1) << 6;   // 0 or 64
  const bool cy = (lane >> 3) & 1;
  const int r   = lane >> 4;

  float acc[8] = {};
  int ib = r;

#pragma unroll 1
  for (int v = 0; v < 6; ++v) {
    const char* sb = (const char*)val_t + (size_t)(v * 8 + h) * (SLENs * 64);
#pragma unroll 1
    for (int l = 0; l < 4; ++l) {
      const int cym = cy ? (2 << (11 - l)) : 0;
#pragma unroll
      for (int i = 0; i < 4; ++i) {
        int ri = ib + i * 4;            // lane r's records: r + ib + 4i
        int bf = Lrb[wid][ri];
        uint2 pk2 = Lrw[wid][ri];
        int voff = ((bf & -64) | e16) + ((bf << 6) & cxm) + ((bf << (11 - l)) & cym);
        uint4 u = *(const uint4*)(sb + voff);
        unsigned int pk = cy ? pk2.y : pk2.x;
        float wl_ = __uint_as_float(cxm ? (pk & 0xFFFF0000u) : (pk << 16));
        acc[0] = fmaf(wl_, __uint_as_float(u.x << 16),          acc[0]);
        acc[1] = fmaf(wl_, __uint_as_float(u.x & 0xFFFF0000u),  acc[1]);
        acc[2] = fmaf(wl_, __uint_as_float(u.y << 16),          acc[2]);
        acc[3] = fmaf(wl_, __uint_as_float(u.y & 0xFFFF0000u),  acc[3]);
        acc[4] = fmaf(wl_, __uint_as_float(u.z << 16),          acc[4]);
        acc[5] = fmaf(wl_, __uint_as_float(u.z & 0xFFFF0000u),  acc[5]);
        acc[6] = fmaf(wl_, __uint_as_float(u.w << 16),          acc[6]);
        acc[7] = fmaf(wl_, __uint_as_float(u.w & 0xFFFF0000u),  acc[7]);
      }
      ib += 16;
    }
  }

#pragma unroll
  for (int m = 4; m <= 32; m <<= 1)
#pragma unroll
    for (int j = 0; j < 8; ++j) acc[j] += __shfl_xor(acc[j], m, 64);

  if (lane < 4) {
    int off = q * EMB + h * 32 + lane * 8;
    ushort4 h0, h1;
    h0.x = f2h(acc[0]); h0.y = f2h(acc[1]); h0.z = f2h(acc[2]); h0.w = f2h(acc[3]);
    h1.x = f2h(acc[4]); h1.y = f2h(acc[5]); h1.z = f2h(acc[6]); h1.w = f2h(acc[7]);
    *(ushort4*)&op16[off] = h0;  *(ushort4*)&op16[off + 4] = h1;
  }
}

// ---------------------------------------------------------------------------
extern "C" void kernel_launch(void* const* d_in, const int* in_sizes, int n_in,
                              void* d_out, int out_size, void* d_ws, size_t ws_size,
                              hipStream_t stream) {
  const float* queries    = (const float*)d_in[0];
  const float* ref_points = (const float*)d_in[1];
  const float* value      = (const float*)d_in[2];
  const float* Wv    = (const float*)d_in[4];
  const float* Woff  = (const float*)d_in[5];
  const float* boff  = (const float*)d_in[6];
  const float* Wattn = (const float*)d_in[7];
  const float* battn = (const float*)d_in[8];
  const float* Wout  = (const float*)d_in[9];
  float* out = (float*)d_out;

  // ws layout, byte offsets — total 69.5 MB (well under proven 155 MB).
  char* W = (char*)d_ws;
  unsigned short* offs16 = (unsigned short*)(W + 0);         // 19,660,800
  unsigned short* attn16 = (unsigned short*)(W + 19660800);  //  9,830,400
  unsigned short* val_t  = (unsigned short*)(W + 29491200);  // 16,711,680 (bf16)
  unsigned short* q16    = (unsigned short*)(W + 46202880);  //    819,200
  unsigned short* v16    = (unsigned short*)(W + 47022080);  // 16,711,680
  unsigned short* Wq16   = (unsigned short*)(W + 63733760);  //  4,718,592 (Woff||Wattn)
  unsigned short* Wv16   = (unsigned short*)(W + 68452352);  //    131,072
  unsigned short* Wout16 = (unsigned short*)(W + 68583424);  //    131,072
  unsigned short* op16   = (unsigned short*)(W + 68714496);  //    819,200

  dim3 blk(256);

  // 1. convert all GEMM operands to fp16 (single-pass)
  split_h_kernel<<<10992, blk, 0, stream>>>(
      queries, value, Woff, Wattn, Wv, Wout, q16, v16, Wq16, Wv16, Wout16);
  // 2. fused offs/attn GEMM: N = 6144 + 3072 = 9216, fp16 in/out
  gemmh_kernel<3><<<dim3(9216 / 128, (QQ + 127) / 128), blk, 0, stream>>>(
      q16, Wq16, boff, battn, offs16, attn16, QQ, 9216, EMB);
  // 3. val_t (bf16, [v][h][s][d]) = (value @ Wv.T) permuted
  gemmh_kernel<2><<<dim3(EMB / 128, (NVv * SLENs) / 128), blk, 0, stream>>>(
      v16, Wv16, nullptr, nullptr, val_t, nullptr, NVv * SLENs, EMB, EMB);
  // 4. fused softmax + record build + sampling -> out_pre fp16
  sample_kernel<<<QQ * NHh / 4, blk, 0, stream>>>(
      ref_points, offs16, attn16, val_t, op16);
  // 5. out = out_pre @ Wout.T (fp16 in, fp32 out)
  gemmh_kernel<0><<<dim3(EMB / 128, (QQ + 127) / 128), blk, 0, stream>>>(
      op16, Wout16, nullptr, nullptr, out, nullptr, QQ, EMB, EMB);
}

// Round 11
// 210.581 us; speedup vs baseline: 6.5897x; 1.1324x over previous
//
#include <hip/hip_runtime.h>
#include <hip/hip_bf16.h>
#include <math.h>

#define NHh   8
#define EMB   256
#define HDd   32
#define NVv   6
#define SLENs 5440
#define QQ    1600
#define A_ATTN 3072   // NH*NV*NL*NP*NZ
#define A_OFF  6144

typedef _Float16 half8 __attribute__((ext_vector_type(8)));
typedef __attribute__((ext_vector_type(4))) float f32x4;

__device__ __forceinline__ unsigned short f2bf(float f) {
  __hip_bfloat16 h = __float2bfloat16(f);
  return *(unsigned short*)&h;
}
__device__ __forceinline__ unsigned short f2h(float f) {
  _Float16 h = (_Float16)f;
  return __builtin_bit_cast(unsigned short, h);
}
__device__ __forceinline__ float h2f(unsigned short u) {
  return (float)__builtin_bit_cast(_Float16, u);
}

// async global->LDS DMA, 16B per lane. LDS dest semantics: wave-uniform base
// + lane*16 (m104/m108) — caller must pass lane-ordered contiguous LDS addrs.
__device__ __forceinline__ void dma16(const unsigned short* g, unsigned short* l) {
  __builtin_amdgcn_global_load_lds(
      (const __attribute__((address_space(1))) unsigned int*)g,
      (__attribute__((address_space(3))) unsigned int*)l, 16, 0, 0);
}

// ---------------------------------------------------------------------------
// One-shot fp32 -> fp16 conversion of all GEMM operands.
// Woff/Wattn land contiguous in Wq16 (Wattn at element 1,572,864).
// ---------------------------------------------------------------------------
__global__ __launch_bounds__(256) void split_h_kernel(
    const float* __restrict__ q, const float* __restrict__ value,
    const float* __restrict__ Woff, const float* __restrict__ Wattn,
    const float* __restrict__ Wv, const float* __restrict__ Wout,
    unsigned short* __restrict__ q16, unsigned short* __restrict__ v16,
    unsigned short* __restrict__ Wq16, unsigned short* __restrict__ Wv16,
    unsigned short* __restrict__ Wout16) {
  int i4 = blockIdx.x * 256 + threadIdx.x;   // < 2,813,952 float4-chunks
  const float* src; unsigned short* dst; int sloc; int dloc;
  if      (i4 < 102400)  { src = q;     dst = q16;    sloc = i4;           dloc = sloc; }
  else if (i4 < 2191360) { src = value; dst = v16;    sloc = i4 - 102400;  dloc = sloc; }
  else if (i4 < 2584576) { src = Woff;  dst = Wq16;   sloc = i4 - 2191360; dloc = sloc; }
  else if (i4 < 2781184) { src = Wattn; dst = Wq16;   sloc = i4 - 2584576; dloc = sloc + 393216; }
  else if (i4 < 2797568) { src = Wv;    dst = Wv16;   sloc = i4 - 2781184; dloc = sloc; }
  else                   { src = Wout;  dst = Wout16; sloc = i4 - 2797568; dloc = sloc; }
  float4 x = ((const float4*)src)[sloc];
  ushort4 hh;
  hh.x = f2h(x.x); hh.y = f2h(x.y); hh.z = f2h(x.z); hh.w = f2h(x.w);
  ((ushort4*)dst)[dloc] = hh;
}

// ---------------------------------------------------------------------------
// Merged fp16 MFMA GEMM (round-11): one dispatch covers
//   blocks [0, 936):    offs/attn GEMM  (M=1600, N=9216, MODE-3 epilogue)
//   blocks [936, 1446): val GEMM        (M=32640, N=256, MODE-2 epilogue)
// 5.6 blocks/CU combined — val-GEMM blocks fill the offs-GEMM's vmcnt-drain
// stalls (round-10 lesson: these GEMMs are latency-bound at 2-3.7 waves/SIMD,
// not staging-BW-bound). Tile 128x128, BK=32, 4 waves 2x2, dma16 staging.
// ---------------------------------------------------------------------------
__global__ __launch_bounds__(256) void gemm23_kernel(
    const unsigned short* __restrict__ q16, const unsigned short* __restrict__ Wq16,
    const unsigned short* __restrict__ v16, const unsigned short* __restrict__ Wv16,
    const float* __restrict__ boff, const float* __restrict__ battn,
    unsigned short* __restrict__ offs16, unsigned short* __restrict__ attn16,
    unsigned short* __restrict__ val_t) {
  __shared__ unsigned short LAh[128 * 32], LBh[128 * 32];

  const int bid = blockIdx.x;
  const unsigned short *A, *B;
  int M, bm, bn;
  bool isVal;
  if (bid < 936) {           // offs/attn: 72 n-tiles x 13 m-tiles
    A = q16;  B = Wq16;  M = QQ;
    bn = (bid % 72) * 128;  bm = (bid / 72) * 128;  isVal = false;
  } else {                   // val: 2 n-tiles x 255 m-tiles
    int b2 = bid - 936;
    A = v16;  B = Wv16;  M = NVv * SLENs;
    bn = (b2 & 1) * 128;  bm = (b2 >> 1) * 128;  isVal = true;
  }
  const int K = EMB;

  const int tid = threadIdx.x;
  const int lane = tid & 63, w = tid >> 6;
  const int wm = (w & 1) * 64, wn = (w >> 1) * 64;
  const int l16 = lane & 15, quad = lane >> 4;

  const int c0 = tid, c1 = tid + 256;
  const int r0 = c0 >> 2, s0 = (c0 & 3) * 8;
  const int r1 = c1 >> 2, s1 = (c1 & 3) * 8;
  const size_t a0 = (size_t)min(bm + r0, M - 1) * K + s0;
  const size_t a1 = (size_t)min(bm + r1, M - 1) * K + s1;
  const size_t b0o = (size_t)(bn + r0) * K + s0;
  const size_t b1o = (size_t)(bn + r1) * K + s1;
  const int l0 = c0 * 8, l1 = c1 * 8;

  f32x4 acc[4][4] = {};

  for (int k0 = 0; k0 < K; k0 += 32) {
    dma16(&A[a0 + k0], &LAh[l0]);
    dma16(&A[a1 + k0], &LAh[l1]);
    dma16(&B[b0o + k0], &LBh[l0]);
    dma16(&B[b1o + k0], &LBh[l1]);
    __syncthreads();

    half8 fa[4], fb[4];
#pragma unroll
    for (int i = 0; i < 4; ++i) {
      int ar = (wm + i * 16 + l16) * 32 + quad * 8;
      int br = (wn + i * 16 + l16) * 32 + quad * 8;
      fa[i] = *(const half8*)&LAh[ar];
      fb[i] = *(const half8*)&LBh[br];
    }
#pragma unroll
    for (int i = 0; i < 4; ++i)
#pragma unroll
      for (int j = 0; j < 4; ++j)
        acc[i][j] = __builtin_amdgcn_mfma_f32_16x16x32_f16(fa[i], fb[j], acc[i][j], 0, 0, 0);
    __syncthreads();
  }

  // epilogue: C/D layout col(n)=lane&15, row(m)=quad*4+reg  [m89-verified]
#pragma unroll
  for (int j = 0; j < 4; ++j) {
    int n = bn + wn + j * 16 + l16;
    float bv = 0.f;
    bool dotanh = false;
    if (!isVal) {
      if (n < A_OFF) { bv = boff[n]; dotanh = true; }
      else bv = battn[n - A_OFF];
    }
#pragma unroll
    for (int i = 0; i < 4; ++i) {
      int mbase = bm + wm + i * 16 + quad * 4;
#pragma unroll
      for (int reg = 0; reg < 4; ++reg) {
        int m = mbase + reg;
        if (m >= M) continue;
        float c = acc[i][j][reg] + bv;
        if (isVal) {   // bf16 permuted store: m=(v*SLEN+s), n=(h*32+d)
          int vv = m / SLENs;
          int s = m - vv * SLENs;
          int hh2 = n >> 5, dd = n & 31;
          val_t[((size_t)(vv * 8 + hh2) * SLENs + s) * 32 + dd] = f2bf(c);
        } else if (dotanh) {
          float t = __expf(2.f * c);
          c = 1.f - 2.f / (t + 1.f);
          offs16[(size_t)m * A_OFF + n] = f2h(c);
        } else {
          attn16[(size_t)m * A_ATTN + (n - A_OFF)] = f2h(c);
        }
      }
    }
  }
}

// ---------------------------------------------------------------------------
// fp16 MFMA GEMM, MODE 0 only (final out = out_pre @ Wout.T, f32 store).
// ---------------------------------------------------------------------------
__global__ __launch_bounds__(256) void gemmh0_kernel(
    const unsigned short* __restrict__ Ah, const unsigned short* __restrict__ Bh,
    float* __restrict__ C, int M, int N, int K) {
  __shared__ unsigned short LAh[128 * 32], LBh[128 * 32];

  const int tid = threadIdx.x;
  const int bm = blockIdx.y * 128, bn = blockIdx.x * 128;
  const int lane = tid & 63, w = tid >> 6;
  const int wm = (w & 1) * 64, wn = (w >> 1) * 64;
  const int l16 = lane & 15, quad = lane >> 4;

  const int c0 = tid, c1 = tid + 256;
  const int r0 = c0 >> 2, s0 = (c0 & 3) * 8;
  const int r1 = c1 >> 2, s1 = (c1 & 3) * 8;
  const size_t a0 = (size_t)min(bm + r0, M - 1) * K + s0;
  const size_t a1 = (size_t)min(bm + r1, M - 1) * K + s1;
  const size_t b0o = (size_t)(bn + r0) * K + s0;
  const size_t b1o = (size_t)(bn + r1) * K + s1;
  const int l0 = c0 * 8, l1 = c1 * 8;

  f32x4 acc[4][4] = {};

  for (int k0 = 0; k0 < K; k0 += 32) {
    dma16(&Ah[a0 + k0], &LAh[l0]);
    dma16(&Ah[a1 + k0], &LAh[l1]);
    dma16(&Bh[b0o + k0], &LBh[l0]);
    dma16(&Bh[b1o + k0], &LBh[l1]);
    __syncthreads();

    half8 fa[4], fb[4];
#pragma unroll
    for (int i = 0; i < 4; ++i) {
      int ar = (wm + i * 16 + l16) * 32 + quad * 8;
      int br = (wn + i * 16 + l16) * 32 + quad * 8;
      fa[i] = *(const half8*)&LAh[ar];
      fb[i] = *(const half8*)&LBh[br];
    }
#pragma unroll
    for (int i = 0; i < 4; ++i)
#pragma unroll
      for (int j = 0; j < 4; ++j)
        acc[i][j] = __builtin_amdgcn_mfma_f32_16x16x32_f16(fa[i], fb[j], acc[i][j], 0, 0, 0);
    __syncthreads();
  }

#pragma unroll
  for (int j = 0; j < 4; ++j) {
    int n = bn + wn + j * 16 + l16;
#pragma unroll
    for (int i = 0; i < 4; ++i) {
      int mbase = bm + wm + i * 16 + quad * 4;
#pragma unroll
      for (int reg = 0; reg < 4; ++reg) {
        int m = mbase + reg;
        if (m >= M) continue;
        C[(size_t)m * N + n] = acc[i][j][reg];
      }
    }
  }
}

// ---------------------------------------------------------------------------
// Fused softmax + record build + sampling. Wave = one (q,h).
// Round-11 change: phase 1 now precomputes ALL FOUR corner byte-offsets per
// record (uint4 in LDS) + 4 corner weights (4x bf16 u16) — phase 2's per-
// record corner math shrinks to ds_read_b32 + ds_read_u16 + shl + add
// (was ~8 VALU of shift/mask/cndmask). Phase-2 hot loop is otherwise the
// round-7-verified v3c: outer loops unroll 1 (round-5 spill lesson), lane
// r's records spaced 4 apart (round-6 lesson), val_t stays bf16.
// ---------------------------------------------------------------------------
__global__ __launch_bounds__(256) void sample_kernel(
    const float* __restrict__ ref, const unsigned short* __restrict__ offs16,
    const unsigned short* __restrict__ attn16,
    const unsigned short* __restrict__ val_t,
    unsigned short* __restrict__ op16) {
  __shared__ int4  Lco[4][384];   // per-record corner byte offsets {o00,o01,o10,o11}
  __shared__ uint2 Lrw[4][384];   // per-record corner weights bf16 {w00,w01,w10,w11}

  const int h   = blockIdx.x & 7;      // XCD L2 affinity: 6 slices ~2.1MB
  const int qt  = blockIdx.x >> 3;
  const int wid = threadIdx.x >> 6;
  const int lane = threadIdx.x & 63;
  const int q   = qt * 4 + wid;
  const int row = q * 8 + h;

  // ---- phase 1: softmax + records ----
  {
    const unsigned short* ap = attn16 + (size_t)row * 384;
    float vals[6];
    float mx = -1e30f;
#pragma unroll
    for (int i = 0; i < 6; ++i) { vals[i] = h2f(ap[lane + i * 64]); mx = fmaxf(mx, vals[i]); }
#pragma unroll
    for (int o = 32; o > 0; o >>= 1) mx = fmaxf(mx, __shfl_xor(mx, o, 64));
    float s = 0.f;
#pragma unroll
    for (int i = 0; i < 6; ++i) { vals[i] = __expf(vals[i] - mx); s += vals[i]; }
#pragma unroll
    for (int o = 32; o > 0; o >>= 1) s += __shfl_xor(s, o, 64);
    const float inv = 1.0f / s;

    const int l = (lane >> 4) & 3;
    const int z = lane & 3;
    const int Wl = 64 >> l;
    const int start = (l == 0) ? 0 : (l == 1 ? 4096 : (l == 2 ? 5120 : 5376));
    const int strideB = 4096 >> l;       // Wl * 64 bytes
    const float sc = 0.5f * (float)(Wl - 1);
    const unsigned int* op = (const unsigned int*)offs16 + (size_t)row * 384;
    const float* rq = ref + (size_t)q * (NVv * 4 * 4 * 2);

#pragma unroll 1
    for (int v = 0; v < 6; ++v) {
      int j = v * 64 + lane;
      float w = vals[v] * inv;
      unsigned int oxy = op[j];              // fp16 pair: lo=x, hi=y
      float ox = h2f((unsigned short)(oxy & 0xFFFF));
      float oy = h2f((unsigned short)(oxy >> 16));
      const float* rp = rq + ((v * 4 + l) * 4 + z) * 2;
      float rx = rp[0], ry = rp[1];
      float x = fminf(1.f, fmaxf(-1.f, rx + ox));
      float y = fminf(1.f, fmaxf(-1.f, ry + oy));
      float xp = (x + 1.f) * sc, yp = (y + 1.f) * sc;
      float x0f = floorf(xp), y0f = floorf(yp);
      int x0 = (int)x0f, y0 = (int)y0f;      // xp,yp >= 0 -> trunc == floor
      float wx = xp - x0f, wy = yp - y0f;
      int b0 = (start + y0 * Wl + x0) << 6;
      int dx = (x0 + 1 < Wl) ? 64 : 0;
      int dy = (y0 + 1 < Wl) ? strideB : 0;
      float wxw = wx * w, wmx = w - wxw;
      float w01 = wxw * (1.f - wy), w11 = wxw * wy;
      float w00 = wmx * (1.f - wy), w10 = wmx * wy;
      Lco[wid][j] = make_int4(b0, b0 + dx, b0 + dy, b0 + dx + dy);
      Lrw[wid][j] = make_uint2(((unsigned)f2bf(w01) << 16) | f2bf(w00),
                               ((unsigned)f2bf(w11) << 16) | f2bf(w10));
    }
  }
  // no __syncthreads: each wave consumes only its own Lco/Lrw slice

  // ---- phase 2: sampling (bf16 val_t) ----
  const int cb  = (lane >> 2) & 3;          // corner index = cx + 2*cy
  const int e16 = (lane & 3) << 4;          // channel-oct byte offset
  const int r   = lane >> 4;

  const int* LcoW = (const int*)&Lco[wid][0];
  const unsigned short* LrwW = (const unsigned short*)&Lrw[wid][0];

  float acc[8] = {};

#pragma unroll 1
  for (int v = 0; v < 6; ++v) {
    const char* sb = (const char*)val_t + (size_t)(v * 8 + h) * (SLENs * 64);
    const int rbase = v * 64 + r;
#pragma unroll 4
    for (int t = 0; t < 16; ++t) {
      int ri = rbase + t * 4;               // lane r's records, spaced 4
      int off = LcoW[ri * 4 + cb];
      float wl_ = __uint_as_float((unsigned int)LrwW[ri * 4 + cb] << 16);
      uint4 u = *(const uint4*)(sb + (off + e16));
      acc[0] = fmaf(wl_, __uint_as_float(u.x << 16),          acc[0]);
      acc[1] = fmaf(wl_, __uint_as_float(u.x & 0xFFFF0000u),  acc[1]);
      acc[2] = fmaf(wl_, __uint_as_float(u.y << 16),          acc[2]);
      acc[3] = fmaf(wl_, __uint_as_float(u.y & 0xFFFF0000u),  acc[3]);
      acc[4] = fmaf(wl_, __uint_as_float(u.z << 16),          acc[4]);
      acc[5] = fmaf(wl_, __uint_as_float(u.z & 0xFFFF0000u),  acc[5]);
      acc[6] = fmaf(wl_, __uint_as_float(u.w << 16),          acc[6]);
      acc[7] = fmaf(wl_, __uint_as_float(u.w & 0xFFFF0000u),  acc[7]);
    }
  }

#pragma unroll
  for (int m = 4; m <= 32; m <<= 1)
#pragma unroll
    for (int j = 0; j < 8; ++j) acc[j] += __shfl_xor(acc[j], m, 64);

  if (lane < 4) {
    int off = q * EMB + h * 32 + lane * 8;
    ushort4 h0, h1;
    h0.x = f2h(acc[0]); h0.y = f2h(acc[1]); h0.z = f2h(acc[2]); h0.w = f2h(acc[3]);
    h1.x = f2h(acc[4]); h1.y = f2h(acc[5]); h1.z = f2h(acc[6]); h1.w = f2h(acc[7]);
    *(ushort4*)&op16[off] = h0;  *(ushort4*)&op16[off + 4] = h1;
  }
}

// ---------------------------------------------------------------------------
extern "C" void kernel_launch(void* const* d_in, const int* in_sizes, int n_in,
                              void* d_out, int out_size, void* d_ws, size_t ws_size,
                              hipStream_t stream) {
  const float* queries    = (const float*)d_in[0];
  const float* ref_points = (const float*)d_in[1];
  const float* value      = (const float*)d_in[2];
  const float* Wv    = (const float*)d_in[4];
  const float* Woff  = (const float*)d_in[5];
  const float* boff  = (const float*)d_in[6];
  const float* Wattn = (const float*)d_in[7];
  const float* battn = (const float*)d_in[8];
  const float* Wout  = (const float*)d_in[9];
  float* out = (float*)d_out;

  // ws layout, byte offsets — total 69.5 MB (well under proven 155 MB).
  char* W = (char*)d_ws;
  unsigned short* offs16 = (unsigned short*)(W + 0);         // 19,660,800
  unsigned short* attn16 = (unsigned short*)(W + 19660800);  //  9,830,400
  unsigned short* val_t  = (unsigned short*)(W + 29491200);  // 16,711,680 (bf16)
  unsigned short* q16    = (unsigned short*)(W + 46202880);  //    819,200
  unsigned short* v16    = (unsigned short*)(W + 47022080);  // 16,711,680
  unsigned short* Wq16   = (unsigned short*)(W + 63733760);  //  4,718,592 (Woff||Wattn)
  unsigned short* Wv16   = (unsigned short*)(W + 68452352);  //    131,072
  unsigned short* Wout16 = (unsigned short*)(W + 68583424);  //    131,072
  unsigned short* op16   = (unsigned short*)(W + 68714496);  //    819,200

  dim3 blk(256);

  // 1. convert all GEMM operands to fp16 (single-pass)
  split_h_kernel<<<10992, blk, 0, stream>>>(
      queries, value, Woff, Wattn, Wv, Wout, q16, v16, Wq16, Wv16, Wout16);
  // 2. merged offs/attn GEMM (936 blocks) + val GEMM (510 blocks)
  gemm23_kernel<<<1446, blk, 0, stream>>>(
      q16, Wq16, v16, Wv16, boff, battn, offs16, attn16, val_t);
  // 3. fused softmax + record build + sampling -> out_pre fp16
  sample_kernel<<<QQ * NHh / 4, blk, 0, stream>>>(
      ref_points, offs16, attn16, val_t, op16);
  // 4. out = out_pre @ Wout.T (fp16 in, fp32 out)
  gemmh0_kernel<<<dim3(EMB / 128, (QQ + 127) / 128), blk, 0, stream>>>(
      op16, Wout16, out, QQ, EMB, EMB);
}